// Round 2
// baseline (1341.032 us; speedup 1.0000x reference)
//
#include <hip/hip_runtime.h>
#include <math.h>

#define DD 128
#define COUT 40
#define BN_EPS 1e-5f
#define L2_EPS 1e-12f

// ---------------- setup kernels ----------------

__global__ void k_init(int* deg, int* fill, int n) {
    int i = blockIdx.x * blockDim.x + threadIdx.x;
    if (i < n) { deg[i] = 1; fill[i] = 0; }   // deg starts at 1 (self loop)
}

__global__ void k_hist(const int* ei, int E, int* deg) {
    int i = blockIdx.x * blockDim.x + threadIdx.x;
    if (i < E) atomicAdd(&deg[ei[E + i]], 1);   // dst = ei[E+i]
}

__global__ void k_dinv(const int* deg, float* dinv, int n) {
    int i = blockIdx.x * blockDim.x + threadIdx.x;
    if (i < n) dinv[i] = rsqrtf((float)deg[i]);
}

// exclusive scan over n+1 entries (deg[i] for i<n, 0 for i==n), 3 phases
__global__ void k_scan_a(const int* deg, int* row_ptr, int* bsum, int n) {
    __shared__ int s[256];
    int t = threadIdx.x;
    int idx = blockIdx.x * 256 + t;
    int v = (idx < n) ? deg[idx] : 0;
    s[t] = v; __syncthreads();
    for (int off = 1; off < 256; off <<= 1) {
        int x = (t >= off) ? s[t - off] : 0;
        __syncthreads(); s[t] += x; __syncthreads();
    }
    if (idx <= n) row_ptr[idx] = s[t] - v;     // local exclusive
    if (t == 255) bsum[blockIdx.x] = s[255];
}

__global__ void k_scan_b(const int* bsum, int* boff, int nb) {
    __shared__ int s[512];
    int t = threadIdx.x;
    int v = (t < nb) ? bsum[t] : 0;
    s[t] = v; __syncthreads();
    for (int off = 1; off < 512; off <<= 1) {
        int x = (t >= off) ? s[t - off] : 0;
        __syncthreads(); s[t] += x; __syncthreads();
    }
    if (t < nb) boff[t] = s[t] - v;            // exclusive block offsets
}

__global__ void k_scan_c(int* row_ptr, const int* boff, int n1) {
    int idx = blockIdx.x * blockDim.x + threadIdx.x;
    if (idx < n1) row_ptr[idx] += boff[idx >> 8];
}

__global__ void k_fill(const int* ei, int E, int n, const int* row_ptr,
                       int* fill, int* colidx) {
    int i = blockIdx.x * blockDim.x + threadIdx.x;
    int total = E + n;
    if (i >= total) return;
    int u, v;
    if (i < E) { u = ei[i]; v = ei[E + i]; }
    else { u = i - E; v = u; }                 // self loop
    int p = atomicAdd(&fill[v], 1);
    colidx[row_ptr[v] + p] = u;
}

// ---------------- compute kernels ----------------

// C[:, half*64 + lane] for 64 rows per block.
// block (64,4): wave w handles rows row0..row0+15, lane -> 1 column.
// B operand staged in LDS, read as conflict-free b32 (bank = lane%32, 2-way free);
// each B float feeds 16 FMAs (one per row accumulator) -> VALU-bound.
__global__ __launch_bounds__(256) void k_gemm(const float* __restrict__ A,
                                              const float* __restrict__ W,
                                              float* __restrict__ C, int nrows) {
    __shared__ float Bs[128 * 64];   // Bs[k][c], 32 KB
    const int lane = threadIdx.x;    // 0..63
    const int wid  = threadIdx.y;    // 0..3
    const int half = blockIdx.y;
    {
        int t = wid * 64 + lane;
        for (int i = t; i < 128 * 16; i += 256) {
            int k = i >> 4, c4 = i & 15;
            *(float4*)&Bs[k * 64 + c4 * 4] =
                *(const float4*)&W[k * 128 + half * 64 + c4 * 4];
        }
    }
    __syncthreads();
    int row0 = (blockIdx.x * 4 + wid) * 16;
    if (row0 >= nrows) return;
    const float* Ab = A + (size_t)row0 * DD;
    float acc[16];
#pragma unroll
    for (int r = 0; r < 16; r++) acc[r] = 0.f;

    if (row0 + 16 <= nrows) {
        for (int kq = 0; kq < 32; kq++) {
            int k0 = kq * 4;
            float b0 = Bs[(k0 + 0) * 64 + lane];
            float b1 = Bs[(k0 + 1) * 64 + lane];
            float b2 = Bs[(k0 + 2) * 64 + lane];
            float b3 = Bs[(k0 + 3) * 64 + lane];
#pragma unroll
            for (int r = 0; r < 16; r++) {
                float4 a = *(const float4*)&Ab[r * DD + k0];   // wave-broadcast load
                acc[r] += a.x * b0 + a.y * b1 + a.z * b2 + a.w * b3;
            }
        }
        float* Cb = C + (size_t)row0 * DD + half * 64 + lane;
#pragma unroll
        for (int r = 0; r < 16; r++) Cb[(size_t)r * DD] = acc[r];
    } else {
        int rmax = nrows - row0;     // 1..15
        for (int kq = 0; kq < 32; kq++) {
            int k0 = kq * 4;
            float b0 = Bs[(k0 + 0) * 64 + lane];
            float b1 = Bs[(k0 + 1) * 64 + lane];
            float b2 = Bs[(k0 + 2) * 64 + lane];
            float b3 = Bs[(k0 + 3) * 64 + lane];
            for (int r = 0; r < rmax; r++) {
                float4 a = *(const float4*)&Ab[r * DD + k0];
                acc[r] += a.x * b0 + a.y * b1 + a.z * b2 + a.w * b3;
            }
        }
        float* Cb = C + (size_t)row0 * DD + half * 64 + lane;
        for (int r = 0; r < rmax; r++) Cb[(size_t)r * DD] = acc[r];
    }
}

// out[v] = bias + sum_{j} dinv[v]*dinv[col[j]] * lin[col[j]]   (one wave per node)
// unroll-2 with dual accumulators for memory-level parallelism on the gather chain
__global__ void k_agg(const float* __restrict__ lin, const int* __restrict__ row_ptr,
                      const int* __restrict__ colidx, const float* __restrict__ dinv,
                      const float* __restrict__ bias, float* __restrict__ out, int n) {
    int v = blockIdx.x * blockDim.y + threadIdx.y;
    if (v >= n) return;
    int lane = threadIdx.x;
    int c = lane * 2;
    int s = row_ptr[v], e = row_ptr[v + 1];
    float dv = dinv[v];
    float2 bi = *(const float2*)&bias[c];
    float ax = bi.x, ay = bi.y;
    float bx = 0.f, by = 0.f;
    int j = s;
    for (; j + 1 < e; j += 2) {
        int u0 = colidx[j], u1 = colidx[j + 1];
        float w0 = dv * dinv[u0];
        float w1 = dv * dinv[u1];
        float2 t0 = *(const float2*)&lin[(size_t)u0 * DD + c];
        float2 t1 = *(const float2*)&lin[(size_t)u1 * DD + c];
        ax += w0 * t0.x; ay += w0 * t0.y;
        bx += w1 * t1.x; by += w1 * t1.y;
    }
    if (j < e) {
        int u = colidx[j];
        float w = dv * dinv[u];
        float2 t = *(const float2*)&lin[(size_t)u * DD + c];
        ax += w * t.x; ay += w * t.y;
    }
    ax += bx; ay += by;
    *(float2*)&out[(size_t)v * DD + c] = make_float2(ax, ay);
}

// partials[b][0..127]=col sums, partials[b][128..255]=col sumsq  (grid must be 256)
__global__ __launch_bounds__(256) void k_bnstats(const float* __restrict__ X, int n,
                                                 float* __restrict__ partials) {
    int cg = (threadIdx.x & 31) * 4;      // column quad
    int rg = threadIdx.x >> 5;            // row group 0..7
    float s0 = 0, s1 = 0, s2 = 0, s3 = 0;
    float q0 = 0, q1 = 0, q2 = 0, q3 = 0;
    for (int r = blockIdx.x * 8 + rg; r < n; r += gridDim.x * 8) {
        float4 x = *(const float4*)&X[(size_t)r * DD + cg];
        s0 += x.x; s1 += x.y; s2 += x.z; s3 += x.w;
        q0 += x.x * x.x; q1 += x.y * x.y; q2 += x.z * x.z; q3 += x.w * x.w;
    }
    __shared__ float sh[8][128];
    __shared__ float qh[8][128];
    sh[rg][cg] = s0; sh[rg][cg + 1] = s1; sh[rg][cg + 2] = s2; sh[rg][cg + 3] = s3;
    qh[rg][cg] = q0; qh[rg][cg + 1] = q1; qh[rg][cg + 2] = q2; qh[rg][cg + 3] = q3;
    __syncthreads();
    if (threadIdx.x < 128) {
        float a = 0, b = 0;
        for (int g = 0; g < 8; g++) { a += sh[g][threadIdx.x]; b += qh[g][threadIdx.x]; }
        partials[blockIdx.x * 256 + threadIdx.x] = a;
        partials[blockIdx.x * 256 + 128 + threadIdx.x] = b;
    }
}

// ss[0..127]=scale, ss[128..255]=shift ; reduces 256 blocks of partials
__global__ void k_bnfinal(const float* __restrict__ partials, const float* g,
                          const float* be, float* ss, float inv_n, int nblk) {
    int c = threadIdx.x;
    float s = 0.f, q = 0.f;
    for (int b = 0; b < nblk; b++) {
        s += partials[b * 256 + c];
        q += partials[b * 256 + 128 + c];
    }
    float mu = s * inv_n;
    float var = q * inv_n - mu * mu;
    float sc = g[c] * rsqrtf(var + BN_EPS);
    ss[c] = sc;
    ss[128 + c] = be[c] - mu * sc;
}

// y = relu(x*scale+shift) (+res); row L2 normalize. One wave per node.
__global__ void k_post(const float* __restrict__ X, const float* __restrict__ ss,
                       const float* __restrict__ res, float* __restrict__ out, int n) {
    int v = blockIdx.x * blockDim.y + threadIdx.y;
    if (v >= n) return;
    int lane = threadIdx.x;
    int c = lane * 2;
    float2 x = *(const float2*)&X[(size_t)v * DD + c];
    float y0 = fmaxf(x.x * ss[c] + ss[128 + c], 0.f);
    float y1 = fmaxf(x.y * ss[c + 1] + ss[128 + c + 1], 0.f);
    if (res) {
        float2 r = *(const float2*)&res[(size_t)v * DD + c];
        y0 += r.x; y1 += r.y;
    }
    float sum = y0 * y0 + y1 * y1;
    for (int m = 1; m < 64; m <<= 1) sum += __shfl_xor(sum, m, 64);
    float inv = 1.f / fmaxf(sqrtf(sum), L2_EPS);
    *(float2*)&out[(size_t)v * DD + c] = make_float2(y0 * inv, y1 * inv);
}

// logits = h @ Wout + bout;  Wout: 128x40. 2 rows/thread, uniform LDS B reads.
__global__ __launch_bounds__(256) void k_outgemm(const float* __restrict__ A,
                                                 const float* __restrict__ W,
                                                 const float* __restrict__ b,
                                                 float* __restrict__ C, int n) {
    __shared__ float Wl[128 * COUT];   // 20 KB
    int t = threadIdx.x;
    for (int i = t; i < 128 * COUT / 4; i += 256)
        *(float4*)&Wl[i * 4] = *(const float4*)&W[i * 4];
    __syncthreads();
    int stride = gridDim.x * 256;
    int r0 = blockIdx.x * 256 + t;
    int r1 = r0 + stride;
    float acc0[COUT], acc1[COUT];
#pragma unroll
    for (int c = 0; c < COUT; c++) { acc0[c] = b[c]; acc1[c] = b[c]; }
    bool h0 = r0 < n, h1 = r1 < n;
    const float* A0 = A + (size_t)(h0 ? r0 : 0) * DD;
    const float* A1 = A + (size_t)(h1 ? r1 : 0) * DD;
    for (int k0 = 0; k0 < 128; k0 += 4) {
        float4 a0 = *(const float4*)(A0 + k0);
        float4 a1 = *(const float4*)(A1 + k0);
        float av0[4] = {a0.x, a0.y, a0.z, a0.w};
        float av1[4] = {a1.x, a1.y, a1.z, a1.w};
#pragma unroll
        for (int kk = 0; kk < 4; kk++) {
            const float* wr = &Wl[(k0 + kk) * COUT];
#pragma unroll
            for (int c = 0; c < COUT; c++) {
                acc0[c] += av0[kk] * wr[c];
                acc1[c] += av1[kk] * wr[c];
            }
        }
    }
    if (h0) {
        float* Cr = C + (size_t)r0 * COUT;
#pragma unroll
        for (int c4 = 0; c4 < COUT / 4; c4++)
            *(float4*)&Cr[c4 * 4] = make_float4(acc0[c4 * 4], acc0[c4 * 4 + 1],
                                                acc0[c4 * 4 + 2], acc0[c4 * 4 + 3]);
    }
    if (h1) {
        float* Cr = C + (size_t)r1 * COUT;
#pragma unroll
        for (int c4 = 0; c4 < COUT / 4; c4++)
            *(float4*)&Cr[c4 * 4] = make_float4(acc1[c4 * 4], acc1[c4 * 4 + 1],
                                                acc1[c4 * 4 + 2], acc1[c4 * 4 + 3]);
    }
}

// ---------------- host ----------------

extern "C" void kernel_launch(void* const* d_in, const int* in_sizes, int n_in,
                              void* d_out, int out_size, void* d_ws, size_t ws_size,
                              hipStream_t stream) {
    const float* x    = (const float*)d_in[0];
    const int*   ei   = (const int*)d_in[1];
    const float* W1   = (const float*)d_in[2];
    const float* b1   = (const float*)d_in[3];
    const float* W2   = (const float*)d_in[4];
    const float* b2   = (const float*)d_in[5];
    const float* W3   = (const float*)d_in[6];
    const float* b3   = (const float*)d_in[7];
    const float* g1   = (const float*)d_in[8];
    const float* be1  = (const float*)d_in[9];
    const float* g2   = (const float*)d_in[10];
    const float* be2  = (const float*)d_in[11];
    const float* g3   = (const float*)d_in[12];
    const float* be3  = (const float*)d_in[13];
    const float* Wout = (const float*)d_in[14];
    const float* bout = (const float*)d_in[15];
    float* out = (float*)d_out;

    const int N = in_sizes[0] / DD;
    const int E = in_sizes[1] / 2;
    const int NNZ = E + N;

    // workspace layout
    char* w = (char*)d_ws;
    float* bufA = (float*)w;                 w += (size_t)N * DD * sizeof(float);
    float* bufB = (float*)w;                 w += (size_t)N * DD * sizeof(float);
    float* bufC = (float*)w;                 w += (size_t)N * DD * sizeof(float);
    int* deg     = (int*)w;                  w += (size_t)N * sizeof(int);
    int* fill    = (int*)w;                  w += (size_t)N * sizeof(int);
    int* row_ptr = (int*)w;                  w += (size_t)(N + 1) * sizeof(int);
    int* colidx  = (int*)w;                  w += (size_t)NNZ * sizeof(int);
    float* dinv  = (float*)w;                w += (size_t)N * sizeof(float);
    int* bsum    = (int*)w;                  w += 512 * sizeof(int);
    int* boff    = (int*)w;                  w += 512 * sizeof(int);
    float* ss    = (float*)w;                w += 256 * sizeof(float);
    float* partials = (float*)w;             w += 256 * 256 * sizeof(float);

    const int NB = (N + 1 + 255) / 256;      // scan blocks
    const int STATS_GRID = 256;

    // ---- CSR build ----
    k_init<<<(N + 255) / 256, 256, 0, stream>>>(deg, fill, N);
    k_hist<<<(E + 255) / 256, 256, 0, stream>>>(ei, E, deg);
    k_dinv<<<(N + 255) / 256, 256, 0, stream>>>(deg, dinv, N);
    k_scan_a<<<NB, 256, 0, stream>>>(deg, row_ptr, bsum, N);
    k_scan_b<<<1, 512, 0, stream>>>(bsum, boff, NB);
    k_scan_c<<<(N + 1 + 255) / 256, 256, 0, stream>>>(row_ptr, boff, N + 1);
    k_fill<<<(NNZ + 255) / 256, 256, 0, stream>>>(ei, E, N, row_ptr, fill, colidx);

    dim3 gemmGrid((N + 63) / 64, 2);
    dim3 gemmBlk(64, 4);
    dim3 waveGrid((N + 3) / 4);
    dim3 waveBlk(64, 4);
    float inv_n = 1.0f / (float)N;
    int outGrid = (N + 511) / 512;

    // ---- layer 1 ----
    k_gemm<<<gemmGrid, gemmBlk, 0, stream>>>(x, W1, bufB, N);
    k_agg<<<waveGrid, waveBlk, 0, stream>>>(bufB, row_ptr, colidx, dinv, b1, bufA, N);
    k_bnstats<<<STATS_GRID, 256, 0, stream>>>(bufA, N, partials);
    k_bnfinal<<<1, 128, 0, stream>>>(partials, g1, be1, ss, inv_n, STATS_GRID);
    k_post<<<waveGrid, waveBlk, 0, stream>>>(bufA, ss, nullptr, bufA, N);   // h1 in bufA

    // ---- layer 2 ----
    k_gemm<<<gemmGrid, gemmBlk, 0, stream>>>(bufA, W2, bufB, N);
    k_agg<<<waveGrid, waveBlk, 0, stream>>>(bufB, row_ptr, colidx, dinv, b2, bufC, N);
    k_bnstats<<<STATS_GRID, 256, 0, stream>>>(bufC, N, partials);
    k_bnfinal<<<1, 128, 0, stream>>>(partials, g2, be2, ss, inv_n, STATS_GRID);
    k_post<<<waveGrid, waveBlk, 0, stream>>>(bufC, ss, bufA, bufC, N);      // h2 in bufC

    // ---- layer 3 ----
    k_gemm<<<gemmGrid, gemmBlk, 0, stream>>>(bufC, W3, bufB, N);
    k_agg<<<waveGrid, waveBlk, 0, stream>>>(bufB, row_ptr, colidx, dinv, b3, bufA, N);
    k_bnstats<<<STATS_GRID, 256, 0, stream>>>(bufA, N, partials);
    k_bnfinal<<<1, 128, 0, stream>>>(partials, g3, be3, ss, inv_n, STATS_GRID);
    k_post<<<waveGrid, waveBlk, 0, stream>>>(bufA, ss, bufC, bufA, N);      // h3 in bufA

    // ---- output ----
    k_outgemm<<<outGrid, 256, 0, stream>>>(bufA, Wout, bout, out, N);
}

// Round 3
// 865.671 us; speedup vs baseline: 1.5491x; 1.5491x over previous
//
#include <hip/hip_runtime.h>
#include <math.h>

#define DD 128
#define COUT 40
#define BN_EPS 1e-5f
#define L2_EPS 1e-12f

// ---------------- setup kernels ----------------

__global__ void k_init(int* deg, int* fill, int n) {
    int i = blockIdx.x * blockDim.x + threadIdx.x;
    if (i < n) { deg[i] = 1; fill[i] = 0; }   // deg starts at 1 (self loop)
}

__global__ void k_hist(const int* ei, int E, int* deg) {
    int i = blockIdx.x * blockDim.x + threadIdx.x;
    if (i < E) atomicAdd(&deg[ei[E + i]], 1);   // dst = ei[E+i]
}

__global__ void k_dinv(const int* deg, float* dinv, int n) {
    int i = blockIdx.x * blockDim.x + threadIdx.x;
    if (i < n) dinv[i] = rsqrtf((float)deg[i]);
}

// exclusive scan over n+1 entries (deg[i] for i<n, 0 for i==n), 3 phases
__global__ void k_scan_a(const int* deg, int* row_ptr, int* bsum, int n) {
    __shared__ int s[256];
    int t = threadIdx.x;
    int idx = blockIdx.x * 256 + t;
    int v = (idx < n) ? deg[idx] : 0;
    s[t] = v; __syncthreads();
    for (int off = 1; off < 256; off <<= 1) {
        int x = (t >= off) ? s[t - off] : 0;
        __syncthreads(); s[t] += x; __syncthreads();
    }
    if (idx <= n) row_ptr[idx] = s[t] - v;     // local exclusive
    if (t == 255) bsum[blockIdx.x] = s[255];
}

__global__ void k_scan_b(const int* bsum, int* boff, int nb) {
    __shared__ int s[512];
    int t = threadIdx.x;
    int v = (t < nb) ? bsum[t] : 0;
    s[t] = v; __syncthreads();
    for (int off = 1; off < 512; off <<= 1) {
        int x = (t >= off) ? s[t - off] : 0;
        __syncthreads(); s[t] += x; __syncthreads();
    }
    if (t < nb) boff[t] = s[t] - v;            // exclusive block offsets
}

__global__ void k_scan_c(int* row_ptr, const int* boff, int n1) {
    int idx = blockIdx.x * blockDim.x + threadIdx.x;
    if (idx < n1) row_ptr[idx] += boff[idx >> 8];
}

__global__ void k_fill(const int* ei, int E, int n, const int* row_ptr,
                       const float* dinv, int* fill, int* colidx, float* wnorm) {
    int i = blockIdx.x * blockDim.x + threadIdx.x;
    int total = E + n;
    if (i >= total) return;
    int u, v;
    if (i < E) { u = ei[i]; v = ei[E + i]; }
    else { u = i - E; v = u; }                 // self loop
    int p = atomicAdd(&fill[v], 1);
    int pos = row_ptr[v] + p;
    colidx[pos] = u;
    wnorm[pos] = dinv[u];
}

// ---------------- compute kernels ----------------

// C = A(nrows x 128) @ W(128 x 128). Register-tiled: block = 256 threads,
// tile 128 rows x 128 cols, K chunked by 32. Thread (tx,ty) in 16x16 grid
// owns an 8x8 sub-tile (64 fp32 accs). A and B staged via LDS with fully
// coalesced 16B/lane global loads; a-frags are 16-lane-broadcast b128 reads.
__global__ __launch_bounds__(256) void k_gemm(const float* __restrict__ A,
                                              const float* __restrict__ W,
                                              float* __restrict__ C, int nrows) {
    __shared__ float As[128][36];   // [m][k] pad 36 -> 16B-aligned rows
    __shared__ float Bs[32][132];   // [k][n] pad 132
    const int tid = threadIdx.x;
    const int tx = tid & 15;        // col group: cols tx*8 .. +7
    const int ty = tid >> 4;        // row group: rows ty*8 .. +7
    const int R0 = blockIdx.x * 128;

    float4 acc0[8], acc1[8];
#pragma unroll
    for (int i = 0; i < 8; i++) {
        acc0[i] = make_float4(0.f, 0.f, 0.f, 0.f);
        acc1[i] = make_float4(0.f, 0.f, 0.f, 0.f);
    }

    for (int kc = 0; kc < 4; kc++) {
        const int k0 = kc * 32;
#pragma unroll
        for (int t = 0; t < 4; t++) {
            int idx = tid + t * 256;
            int row = idx >> 3, kq = idx & 7;           // A: 128 rows x 8 f4
            int gr = R0 + row; if (gr >= nrows) gr = nrows - 1;
            *(float4*)&As[row][kq * 4] =
                *(const float4*)&A[(size_t)gr * DD + k0 + kq * 4];
            int kk = idx >> 5, nq = idx & 31;           // B: 32 k x 32 f4
            *(float4*)&Bs[kk][nq * 4] =
                *(const float4*)&W[(size_t)(k0 + kk) * DD + nq * 4];
        }
        __syncthreads();
#pragma unroll
        for (int kq = 0; kq < 8; kq++) {
            float4 a[8];
#pragma unroll
            for (int i = 0; i < 8; i++) a[i] = *(const float4*)&As[ty * 8 + i][kq * 4];
#pragma unroll
            for (int kk = 0; kk < 4; kk++) {
                float4 b0 = *(const float4*)&Bs[kq * 4 + kk][tx * 8];
                float4 b1 = *(const float4*)&Bs[kq * 4 + kk][tx * 8 + 4];
#pragma unroll
                for (int i = 0; i < 8; i++) {
                    float ak = (kk == 0) ? a[i].x : (kk == 1) ? a[i].y
                             : (kk == 2) ? a[i].z : a[i].w;
                    acc0[i].x += ak * b0.x; acc0[i].y += ak * b0.y;
                    acc0[i].z += ak * b0.z; acc0[i].w += ak * b0.w;
                    acc1[i].x += ak * b1.x; acc1[i].y += ak * b1.y;
                    acc1[i].z += ak * b1.z; acc1[i].w += ak * b1.w;
                }
            }
        }
        __syncthreads();
    }

#pragma unroll
    for (int i = 0; i < 8; i++) {
        int r = R0 + ty * 8 + i;
        if (r < nrows) {
            *(float4*)&C[(size_t)r * DD + tx * 8] = acc0[i];
            *(float4*)&C[(size_t)r * DD + tx * 8 + 4] = acc1[i];
        }
    }
}

// out[v] = bias + dv * sum_j wnorm[j] * lin[col[j]]; 2 nodes per wave
// (32 lanes/node, float4 per lane), unroll-2 dual accumulators.
__global__ void k_agg(const float* __restrict__ lin, const int* __restrict__ row_ptr,
                      const int* __restrict__ colidx, const float* __restrict__ wnorm,
                      const float* __restrict__ dinv, const float* __restrict__ bias,
                      float* __restrict__ out, int n) {
    int lane = threadIdx.x;
    int half = lane >> 5;
    int li = lane & 31;
    int v = blockIdx.x * 8 + threadIdx.y * 2 + half;
    if (v >= n) return;
    int c = li * 4;
    int s = row_ptr[v], e = row_ptr[v + 1];
    float dv = dinv[v];
    float4 accA = *(const float4*)&bias[c];
    float4 accB = make_float4(0.f, 0.f, 0.f, 0.f);
    int j = s;
    for (; j + 1 < e; j += 2) {
        int u0 = colidx[j], u1 = colidx[j + 1];
        float w0 = dv * wnorm[j];
        float w1 = dv * wnorm[j + 1];
        float4 t0 = *(const float4*)&lin[(size_t)u0 * DD + c];
        float4 t1 = *(const float4*)&lin[(size_t)u1 * DD + c];
        accA.x += w0 * t0.x; accA.y += w0 * t0.y;
        accA.z += w0 * t0.z; accA.w += w0 * t0.w;
        accB.x += w1 * t1.x; accB.y += w1 * t1.y;
        accB.z += w1 * t1.z; accB.w += w1 * t1.w;
    }
    if (j < e) {
        int u = colidx[j];
        float w = dv * wnorm[j];
        float4 t = *(const float4*)&lin[(size_t)u * DD + c];
        accA.x += w * t.x; accA.y += w * t.y;
        accA.z += w * t.z; accA.w += w * t.w;
    }
    accA.x += accB.x; accA.y += accB.y; accA.z += accB.z; accA.w += accB.w;
    *(float4*)&out[(size_t)v * DD + c] = accA;
}

// partials[b][0..127]=col sums, partials[b][128..255]=col sumsq  (grid must be 256)
__global__ __launch_bounds__(256) void k_bnstats(const float* __restrict__ X, int n,
                                                 float* __restrict__ partials) {
    int cg = (threadIdx.x & 31) * 4;      // column quad
    int rg = threadIdx.x >> 5;            // row group 0..7
    float s0 = 0, s1 = 0, s2 = 0, s3 = 0;
    float q0 = 0, q1 = 0, q2 = 0, q3 = 0;
    for (int r = blockIdx.x * 8 + rg; r < n; r += gridDim.x * 8) {
        float4 x = *(const float4*)&X[(size_t)r * DD + cg];
        s0 += x.x; s1 += x.y; s2 += x.z; s3 += x.w;
        q0 += x.x * x.x; q1 += x.y * x.y; q2 += x.z * x.z; q3 += x.w * x.w;
    }
    __shared__ float sh[8][128];
    __shared__ float qh[8][128];
    sh[rg][cg] = s0; sh[rg][cg + 1] = s1; sh[rg][cg + 2] = s2; sh[rg][cg + 3] = s3;
    qh[rg][cg] = q0; qh[rg][cg + 1] = q1; qh[rg][cg + 2] = q2; qh[rg][cg + 3] = q3;
    __syncthreads();
    if (threadIdx.x < 128) {
        float a = 0, b = 0;
        for (int g = 0; g < 8; g++) { a += sh[g][threadIdx.x]; b += qh[g][threadIdx.x]; }
        partials[blockIdx.x * 256 + threadIdx.x] = a;
        partials[blockIdx.x * 256 + 128 + threadIdx.x] = b;
    }
}

// ss[0..127]=scale, ss[128..255]=shift ; reduces partial blocks
__global__ void k_bnfinal(const float* __restrict__ partials, const float* g,
                          const float* be, float* ss, float inv_n, int nblk) {
    int c = threadIdx.x;
    float s = 0.f, q = 0.f;
    for (int b = 0; b < nblk; b++) {
        s += partials[b * 256 + c];
        q += partials[b * 256 + 128 + c];
    }
    float mu = s * inv_n;
    float var = q * inv_n - mu * mu;
    float sc = g[c] * rsqrtf(var + BN_EPS);
    ss[c] = sc;
    ss[128 + c] = be[c] - mu * sc;
}

// y = relu(x*scale+shift) (+res); row L2 normalize. One wave per node.
__global__ void k_post(const float* __restrict__ X, const float* __restrict__ ss,
                       const float* __restrict__ res, float* __restrict__ out, int n) {
    int v = blockIdx.x * blockDim.y + threadIdx.y;
    if (v >= n) return;
    int lane = threadIdx.x;
    int c = lane * 2;
    float2 x = *(const float2*)&X[(size_t)v * DD + c];
    float y0 = fmaxf(x.x * ss[c] + ss[128 + c], 0.f);
    float y1 = fmaxf(x.y * ss[c + 1] + ss[128 + c + 1], 0.f);
    if (res) {
        float2 r = *(const float2*)&res[(size_t)v * DD + c];
        y0 += r.x; y1 += r.y;
    }
    float sum = y0 * y0 + y1 * y1;
    for (int m = 1; m < 64; m <<= 1) sum += __shfl_xor(sum, m, 64);
    float inv = 1.f / fmaxf(sqrtf(sum), L2_EPS);
    *(float2*)&out[(size_t)v * DD + c] = make_float2(y0 * inv, y1 * inv);
}

// logits = h @ Wout + bout;  Wout: 128x40. 2 rows/thread, uniform LDS B reads.
__global__ __launch_bounds__(256) void k_outgemm(const float* __restrict__ A,
                                                 const float* __restrict__ W,
                                                 const float* __restrict__ b,
                                                 float* __restrict__ C, int n) {
    __shared__ float Wl[128 * COUT];   // 20 KB
    int t = threadIdx.x;
    for (int i = t; i < 128 * COUT / 4; i += 256)
        *(float4*)&Wl[i * 4] = *(const float4*)&W[i * 4];
    __syncthreads();
    int stride = gridDim.x * 256;
    int r0 = blockIdx.x * 256 + t;
    int r1 = r0 + stride;
    float acc0[COUT], acc1[COUT];
#pragma unroll
    for (int c = 0; c < COUT; c++) { acc0[c] = b[c]; acc1[c] = b[c]; }
    bool h0 = r0 < n, h1 = r1 < n;
    const float* A0 = A + (size_t)(h0 ? r0 : 0) * DD;
    const float* A1 = A + (size_t)(h1 ? r1 : 0) * DD;
    for (int k0 = 0; k0 < 128; k0 += 4) {
        float4 a0 = *(const float4*)(A0 + k0);
        float4 a1 = *(const float4*)(A1 + k0);
        float av0[4] = {a0.x, a0.y, a0.z, a0.w};
        float av1[4] = {a1.x, a1.y, a1.z, a1.w};
#pragma unroll
        for (int kk = 0; kk < 4; kk++) {
            const float* wr = &Wl[(k0 + kk) * COUT];
#pragma unroll
            for (int c = 0; c < COUT; c++) {
                acc0[c] += av0[kk] * wr[c];
                acc1[c] += av1[kk] * wr[c];
            }
        }
    }
    if (h0) {
        float* Cr = C + (size_t)r0 * COUT;
#pragma unroll
        for (int c4 = 0; c4 < COUT / 4; c4++)
            *(float4*)&Cr[c4 * 4] = make_float4(acc0[c4 * 4], acc0[c4 * 4 + 1],
                                                acc0[c4 * 4 + 2], acc0[c4 * 4 + 3]);
    }
    if (h1) {
        float* Cr = C + (size_t)r1 * COUT;
#pragma unroll
        for (int c4 = 0; c4 < COUT / 4; c4++)
            *(float4*)&Cr[c4 * 4] = make_float4(acc1[c4 * 4], acc1[c4 * 4 + 1],
                                                acc1[c4 * 4 + 2], acc1[c4 * 4 + 3]);
    }
}

// ---------------- host ----------------

extern "C" void kernel_launch(void* const* d_in, const int* in_sizes, int n_in,
                              void* d_out, int out_size, void* d_ws, size_t ws_size,
                              hipStream_t stream) {
    const float* x    = (const float*)d_in[0];
    const int*   ei   = (const int*)d_in[1];
    const float* W1   = (const float*)d_in[2];
    const float* b1   = (const float*)d_in[3];
    const float* W2   = (const float*)d_in[4];
    const float* b2   = (const float*)d_in[5];
    const float* W3   = (const float*)d_in[6];
    const float* b3   = (const float*)d_in[7];
    const float* g1   = (const float*)d_in[8];
    const float* be1  = (const float*)d_in[9];
    const float* g2   = (const float*)d_in[10];
    const float* be2  = (const float*)d_in[11];
    const float* g3   = (const float*)d_in[12];
    const float* be3  = (const float*)d_in[13];
    const float* Wout = (const float*)d_in[14];
    const float* bout = (const float*)d_in[15];
    float* out = (float*)d_out;

    const int N = in_sizes[0] / DD;
    const int E = in_sizes[1] / 2;
    const int NNZ = E + N;

    // workspace layout
    char* w = (char*)d_ws;
    float* bufA = (float*)w;                 w += (size_t)N * DD * sizeof(float);
    float* bufB = (float*)w;                 w += (size_t)N * DD * sizeof(float);
    float* bufC = (float*)w;                 w += (size_t)N * DD * sizeof(float);
    int* deg     = (int*)w;                  w += (size_t)N * sizeof(int);
    int* fill    = (int*)w;                  w += (size_t)N * sizeof(int);
    int* row_ptr = (int*)w;                  w += (size_t)(N + 1) * sizeof(int);
    int* colidx  = (int*)w;                  w += (size_t)NNZ * sizeof(int);
    float* wnorm = (float*)w;                w += (size_t)NNZ * sizeof(float);
    float* dinv  = (float*)w;                w += (size_t)N * sizeof(float);
    int* bsum    = (int*)w;                  w += 512 * sizeof(int);
    int* boff    = (int*)w;                  w += 512 * sizeof(int);
    float* ss    = (float*)w;                w += 256 * sizeof(float);
    float* partials = (float*)w;             w += 256 * 256 * sizeof(float);

    const int NB = (N + 1 + 255) / 256;      // scan blocks
    const int STATS_GRID = 256;

    // ---- CSR build ----
    k_init<<<(N + 255) / 256, 256, 0, stream>>>(deg, fill, N);
    k_hist<<<(E + 255) / 256, 256, 0, stream>>>(ei, E, deg);
    k_dinv<<<(N + 255) / 256, 256, 0, stream>>>(deg, dinv, N);
    k_scan_a<<<NB, 256, 0, stream>>>(deg, row_ptr, bsum, N);
    k_scan_b<<<1, 512, 0, stream>>>(bsum, boff, NB);
    k_scan_c<<<(N + 1 + 255) / 256, 256, 0, stream>>>(row_ptr, boff, N + 1);
    k_fill<<<(NNZ + 255) / 256, 256, 0, stream>>>(ei, E, N, row_ptr, dinv, fill, colidx, wnorm);

    int gemmGrid = (N + 127) / 128;
    dim3 aggGrid((N + 7) / 8);
    dim3 aggBlk(64, 4);
    dim3 postGrid((N + 3) / 4);
    dim3 postBlk(64, 4);
    float inv_n = 1.0f / (float)N;
    int outGrid = (N + 511) / 512;

    // ---- layer 1 ----
    k_gemm<<<gemmGrid, 256, 0, stream>>>(x, W1, bufB, N);
    k_agg<<<aggGrid, aggBlk, 0, stream>>>(bufB, row_ptr, colidx, wnorm, dinv, b1, bufA, N);
    k_bnstats<<<STATS_GRID, 256, 0, stream>>>(bufA, N, partials);
    k_bnfinal<<<1, 128, 0, stream>>>(partials, g1, be1, ss, inv_n, STATS_GRID);
    k_post<<<postGrid, postBlk, 0, stream>>>(bufA, ss, nullptr, bufA, N);   // h1 in bufA

    // ---- layer 2 ----
    k_gemm<<<gemmGrid, 256, 0, stream>>>(bufA, W2, bufB, N);
    k_agg<<<aggGrid, aggBlk, 0, stream>>>(bufB, row_ptr, colidx, wnorm, dinv, b2, bufC, N);
    k_bnstats<<<STATS_GRID, 256, 0, stream>>>(bufC, N, partials);
    k_bnfinal<<<1, 128, 0, stream>>>(partials, g2, be2, ss, inv_n, STATS_GRID);
    k_post<<<postGrid, postBlk, 0, stream>>>(bufC, ss, bufA, bufC, N);      // h2 in bufC

    // ---- layer 3 ----
    k_gemm<<<gemmGrid, 256, 0, stream>>>(bufC, W3, bufB, N);
    k_agg<<<aggGrid, aggBlk, 0, stream>>>(bufB, row_ptr, colidx, wnorm, dinv, b3, bufA, N);
    k_bnstats<<<STATS_GRID, 256, 0, stream>>>(bufA, N, partials);
    k_bnfinal<<<1, 128, 0, stream>>>(partials, g3, be3, ss, inv_n, STATS_GRID);
    k_post<<<postGrid, postBlk, 0, stream>>>(bufA, ss, bufC, bufA, N);      // h3 in bufA

    // ---- output ----
    k_outgemm<<<outGrid, 256, 0, stream>>>(bufA, Wout, bout, out, N);
}

// Round 4
// 776.541 us; speedup vs baseline: 1.7269x; 1.1148x over previous
//
#include <hip/hip_runtime.h>
#include <math.h>

#define DD 128
#define COUT 40
#define BN_EPS 1e-5f
#define L2_EPS 1e-12f

typedef __attribute__((ext_vector_type(8))) short bf16x8;
typedef __attribute__((ext_vector_type(4))) float f32x4;

static __device__ inline unsigned short f2bf(float f) {
    unsigned int x = __float_as_uint(f);
    unsigned int r = (x + 0x7FFFu + ((x >> 16) & 1u)) >> 16;   // RNE
    return (unsigned short)r;
}

// ---------------- setup kernels ----------------

__global__ void k_init(int* deg, int* fill, int n) {
    int i = blockIdx.x * blockDim.x + threadIdx.x;
    if (i < n) { deg[i] = 1; fill[i] = 0; }   // deg starts at 1 (self loop)
}

__global__ void k_hist(const int* ei, int E, int* deg) {
    int i = blockIdx.x * blockDim.x + threadIdx.x;
    if (i < E) atomicAdd(&deg[ei[E + i]], 1);   // dst = ei[E+i]
}

__global__ void k_dinv(const int* deg, float* dinv, int n) {
    int i = blockIdx.x * blockDim.x + threadIdx.x;
    if (i < n) dinv[i] = rsqrtf((float)deg[i]);
}

// exclusive scan over n+1 entries, 3 phases
__global__ void k_scan_a(const int* deg, int* row_ptr, int* bsum, int n) {
    __shared__ int s[256];
    int t = threadIdx.x;
    int idx = blockIdx.x * 256 + t;
    int v = (idx < n) ? deg[idx] : 0;
    s[t] = v; __syncthreads();
    for (int off = 1; off < 256; off <<= 1) {
        int x = (t >= off) ? s[t - off] : 0;
        __syncthreads(); s[t] += x; __syncthreads();
    }
    if (idx <= n) row_ptr[idx] = s[t] - v;     // local exclusive
    if (t == 255) bsum[blockIdx.x] = s[255];
}

__global__ void k_scan_b(const int* bsum, int* boff, int nb) {
    __shared__ int s[512];
    int t = threadIdx.x;
    int v = (t < nb) ? bsum[t] : 0;
    s[t] = v; __syncthreads();
    for (int off = 1; off < 512; off <<= 1) {
        int x = (t >= off) ? s[t - off] : 0;
        __syncthreads(); s[t] += x; __syncthreads();
    }
    if (t < nb) boff[t] = s[t] - v;            // exclusive block offsets
}

__global__ void k_scan_c(int* row_ptr, const int* boff, int n1) {
    int idx = blockIdx.x * blockDim.x + threadIdx.x;
    if (idx < n1) row_ptr[idx] += boff[idx >> 8];
}

__global__ void k_fill(const int* ei, int E, int n, const int* row_ptr,
                       const float* dinv, int* fill, int* colidx, float* wnorm) {
    int i = blockIdx.x * blockDim.x + threadIdx.x;
    int total = E + n;
    if (i >= total) return;
    int u, v;
    if (i < E) { u = ei[i]; v = ei[E + i]; }
    else { u = i - E; v = u; }                 // self loop
    int p = atomicAdd(&fill[v], 1);
    int pos = row_ptr[v] + p;
    colidx[pos] = u;
    wnorm[pos] = dinv[u];
}

// repack W (128x128 fp32, row-major [k][n]) into bf16 B-fragment order:
// out[((kc*8+cc)*64 + lane)*8 + j] = bf16( W[(kc*32 + (lane>>4)*8 + j)*128 + cc*16 + (lane&15)] )
__global__ void k_wrepack(const float* __restrict__ W, unsigned short* __restrict__ out) {
    int idx = blockIdx.x * 256 + threadIdx.x;      // 0..2047
    int kc = idx >> 9;
    int cc = (idx >> 6) & 7;
    int lane = idx & 63;
    int n = cc * 16 + (lane & 15);
    int kb = kc * 32 + (lane >> 4) * 8;
    unsigned short tmp[8];
#pragma unroll
    for (int j = 0; j < 8; j++) tmp[j] = f2bf(W[(size_t)(kb + j) * DD + n]);
    uint4* dst = (uint4*)&out[(size_t)idx * 8];
    *dst = *(const uint4*)tmp;
}

// ---------------- compute kernels ----------------

// C = A(nrows x 128, fp32) @ W(128x128), MFMA bf16. Block = 4 waves, 64 rows.
// Wb (bf16 fragment-packed, 32 KB) staged once to LDS; K-loop is pure
// ds_read_b128 + v_mfma, no barriers. A converted fp32->bf16 in-register.
__global__ __launch_bounds__(256) void k_gemm_mfma(const float* __restrict__ A,
                                                   const unsigned short* __restrict__ Wb,
                                                   float* __restrict__ C, int nrows) {
    __shared__ __align__(16) unsigned short Ws[16384];   // 32 KB
    const int tid = threadIdx.x;
    for (int i = tid; i < 2048; i += 256)
        ((uint4*)Ws)[i] = ((const uint4*)Wb)[i];
    __syncthreads();

    const int wv = tid >> 6;
    const int lane = tid & 63;
    const int R0 = blockIdx.x * 64 + wv * 16;
    if (R0 >= nrows) return;
    const int m = lane & 15, q = lane >> 4;

    int rr = R0 + m; if (rr >= nrows) rr = nrows - 1;
    const float* Ar = A + (size_t)rr * DD + q * 8;

    bf16x8 af[4];
#pragma unroll
    for (int kc = 0; kc < 4; kc++) {
        float4 lo = *(const float4*)(Ar + kc * 32);
        float4 hi = *(const float4*)(Ar + kc * 32 + 4);
        unsigned short t[8];
        t[0] = f2bf(lo.x); t[1] = f2bf(lo.y); t[2] = f2bf(lo.z); t[3] = f2bf(lo.w);
        t[4] = f2bf(hi.x); t[5] = f2bf(hi.y); t[6] = f2bf(hi.z); t[7] = f2bf(hi.w);
        af[kc] = *(const bf16x8*)t;
    }

    f32x4 acc[8];
#pragma unroll
    for (int cc = 0; cc < 8; cc++) acc[cc] = (f32x4){0.f, 0.f, 0.f, 0.f};

#pragma unroll
    for (int kc = 0; kc < 4; kc++) {
#pragma unroll
        for (int cc = 0; cc < 8; cc++) {
            bf16x8 b = *(const bf16x8*)&Ws[(size_t)((kc * 8 + cc) * 64 + lane) * 8];
            acc[cc] = __builtin_amdgcn_mfma_f32_16x16x32_bf16(af[kc], b, acc[cc], 0, 0, 0);
        }
    }

    // C/D layout: col = lane&15 (=m), row = q*4 + reg
#pragma unroll
    for (int cc = 0; cc < 8; cc++) {
#pragma unroll
        for (int i = 0; i < 4; i++) {
            int r = R0 + q * 4 + i;
            if (r < nrows) C[(size_t)r * DD + cc * 16 + m] = acc[cc][i];
        }
    }
}

// out[v] = bias + dv * sum_j wnorm[j] * lin[col[j]]; 2 nodes per wave
__global__ void k_agg(const float* __restrict__ lin, const int* __restrict__ row_ptr,
                      const int* __restrict__ colidx, const float* __restrict__ wnorm,
                      const float* __restrict__ dinv, const float* __restrict__ bias,
                      float* __restrict__ out, int n) {
    int lane = threadIdx.x;
    int half = lane >> 5;
    int li = lane & 31;
    int v = blockIdx.x * 8 + threadIdx.y * 2 + half;
    if (v >= n) return;
    int c = li * 4;
    int s = row_ptr[v], e = row_ptr[v + 1];
    float dv = dinv[v];
    float4 accA = *(const float4*)&bias[c];
    float4 accB = make_float4(0.f, 0.f, 0.f, 0.f);
    int j = s;
    for (; j + 1 < e; j += 2) {
        int u0 = colidx[j], u1 = colidx[j + 1];
        float w0 = dv * wnorm[j];
        float w1 = dv * wnorm[j + 1];
        float4 t0 = *(const float4*)&lin[(size_t)u0 * DD + c];
        float4 t1 = *(const float4*)&lin[(size_t)u1 * DD + c];
        accA.x += w0 * t0.x; accA.y += w0 * t0.y;
        accA.z += w0 * t0.z; accA.w += w0 * t0.w;
        accB.x += w1 * t1.x; accB.y += w1 * t1.y;
        accB.z += w1 * t1.z; accB.w += w1 * t1.w;
    }
    if (j < e) {
        int u = colidx[j];
        float w = dv * wnorm[j];
        float4 t = *(const float4*)&lin[(size_t)u * DD + c];
        accA.x += w * t.x; accA.y += w * t.y;
        accA.z += w * t.z; accA.w += w * t.w;
    }
    accA.x += accB.x; accA.y += accB.y; accA.z += accB.z; accA.w += accB.w;
    *(float4*)&out[(size_t)v * DD + c] = accA;
}

// partials[b][0..127]=col sums, partials[b][128..255]=col sumsq  (grid must be 256)
__global__ __launch_bounds__(256) void k_bnstats(const float* __restrict__ X, int n,
                                                 float* __restrict__ partials) {
    int cg = (threadIdx.x & 31) * 4;
    int rg = threadIdx.x >> 5;
    float s0 = 0, s1 = 0, s2 = 0, s3 = 0;
    float q0 = 0, q1 = 0, q2 = 0, q3 = 0;
    for (int r = blockIdx.x * 8 + rg; r < n; r += gridDim.x * 8) {
        float4 x = *(const float4*)&X[(size_t)r * DD + cg];
        s0 += x.x; s1 += x.y; s2 += x.z; s3 += x.w;
        q0 += x.x * x.x; q1 += x.y * x.y; q2 += x.z * x.z; q3 += x.w * x.w;
    }
    __shared__ float sh[8][128];
    __shared__ float qh[8][128];
    sh[rg][cg] = s0; sh[rg][cg + 1] = s1; sh[rg][cg + 2] = s2; sh[rg][cg + 3] = s3;
    qh[rg][cg] = q0; qh[rg][cg + 1] = q1; qh[rg][cg + 2] = q2; qh[rg][cg + 3] = q3;
    __syncthreads();
    if (threadIdx.x < 128) {
        float a = 0, b = 0;
        for (int g = 0; g < 8; g++) { a += sh[g][threadIdx.x]; b += qh[g][threadIdx.x]; }
        partials[blockIdx.x * 256 + threadIdx.x] = a;
        partials[blockIdx.x * 256 + 128 + threadIdx.x] = b;
    }
}

__global__ void k_bnfinal(const float* __restrict__ partials, const float* g,
                          const float* be, float* ss, float inv_n, int nblk) {
    int c = threadIdx.x;
    float s = 0.f, q = 0.f;
    for (int b = 0; b < nblk; b++) {
        s += partials[b * 256 + c];
        q += partials[b * 256 + 128 + c];
    }
    float mu = s * inv_n;
    float var = q * inv_n - mu * mu;
    float sc = g[c] * rsqrtf(var + BN_EPS);
    ss[c] = sc;
    ss[128 + c] = be[c] - mu * sc;
}

// y = relu(x*scale+shift) (+res); row L2 normalize. One wave per node.
__global__ void k_post(const float* __restrict__ X, const float* __restrict__ ss,
                       const float* __restrict__ res, float* __restrict__ out, int n) {
    int v = blockIdx.x * blockDim.y + threadIdx.y;
    if (v >= n) return;
    int lane = threadIdx.x;
    int c = lane * 2;
    float2 x = *(const float2*)&X[(size_t)v * DD + c];
    float y0 = fmaxf(x.x * ss[c] + ss[128 + c], 0.f);
    float y1 = fmaxf(x.y * ss[c + 1] + ss[128 + c + 1], 0.f);
    if (res) {
        float2 r = *(const float2*)&res[(size_t)v * DD + c];
        y0 += r.x; y1 += r.y;
    }
    float sum = y0 * y0 + y1 * y1;
    for (int m = 1; m < 64; m <<= 1) sum += __shfl_xor(sum, m, 64);
    float inv = 1.f / fmaxf(sqrtf(sum), L2_EPS);
    *(float2*)&out[(size_t)v * DD + c] = make_float2(y0 * inv, y1 * inv);
}

// logits = h @ Wout + bout;  Wout: 128x40. 2 rows/thread, uniform LDS B reads.
__global__ __launch_bounds__(256) void k_outgemm(const float* __restrict__ A,
                                                 const float* __restrict__ W,
                                                 const float* __restrict__ b,
                                                 float* __restrict__ C, int n) {
    __shared__ float Wl[128 * COUT];   // 20 KB
    int t = threadIdx.x;
    for (int i = t; i < 128 * COUT / 4; i += 256)
        *(float4*)&Wl[i * 4] = *(const float4*)&W[i * 4];
    __syncthreads();
    int stride = gridDim.x * 256;
    int r0 = blockIdx.x * 256 + t;
    int r1 = r0 + stride;
    float acc0[COUT], acc1[COUT];
#pragma unroll
    for (int c = 0; c < COUT; c++) { acc0[c] = b[c]; acc1[c] = b[c]; }
    bool h0 = r0 < n, h1 = r1 < n;
    const float* A0 = A + (size_t)(h0 ? r0 : 0) * DD;
    const float* A1 = A + (size_t)(h1 ? r1 : 0) * DD;
    for (int k0 = 0; k0 < 128; k0 += 4) {
        float4 a0 = *(const float4*)(A0 + k0);
        float4 a1 = *(const float4*)(A1 + k0);
        float av0[4] = {a0.x, a0.y, a0.z, a0.w};
        float av1[4] = {a1.x, a1.y, a1.z, a1.w};
#pragma unroll
        for (int kk = 0; kk < 4; kk++) {
            const float* wr = &Wl[(k0 + kk) * COUT];
#pragma unroll
            for (int c = 0; c < COUT; c++) {
                acc0[c] += av0[kk] * wr[c];
                acc1[c] += av1[kk] * wr[c];
            }
        }
    }
    if (h0) {
        float* Cr = C + (size_t)r0 * COUT;
#pragma unroll
        for (int c4 = 0; c4 < COUT / 4; c4++)
            *(float4*)&Cr[c4 * 4] = make_float4(acc0[c4 * 4], acc0[c4 * 4 + 1],
                                                acc0[c4 * 4 + 2], acc0[c4 * 4 + 3]);
    }
    if (h1) {
        float* Cr = C + (size_t)r1 * COUT;
#pragma unroll
        for (int c4 = 0; c4 < COUT / 4; c4++)
            *(float4*)&Cr[c4 * 4] = make_float4(acc1[c4 * 4], acc1[c4 * 4 + 1],
                                                acc1[c4 * 4 + 2], acc1[c4 * 4 + 3]);
    }
}

// ---------------- host ----------------

extern "C" void kernel_launch(void* const* d_in, const int* in_sizes, int n_in,
                              void* d_out, int out_size, void* d_ws, size_t ws_size,
                              hipStream_t stream) {
    const float* x    = (const float*)d_in[0];
    const int*   ei   = (const int*)d_in[1];
    const float* W1   = (const float*)d_in[2];
    const float* b1   = (const float*)d_in[3];
    const float* W2   = (const float*)d_in[4];
    const float* b2   = (const float*)d_in[5];
    const float* W3   = (const float*)d_in[6];
    const float* b3   = (const float*)d_in[7];
    const float* g1   = (const float*)d_in[8];
    const float* be1  = (const float*)d_in[9];
    const float* g2   = (const float*)d_in[10];
    const float* be2  = (const float*)d_in[11];
    const float* g3   = (const float*)d_in[12];
    const float* be3  = (const float*)d_in[13];
    const float* Wout = (const float*)d_in[14];
    const float* bout = (const float*)d_in[15];
    float* out = (float*)d_out;

    const int N = in_sizes[0] / DD;
    const int E = in_sizes[1] / 2;
    const int NNZ = E + N;

    // workspace layout
    char* w = (char*)d_ws;
    float* bufA = (float*)w;                 w += (size_t)N * DD * sizeof(float);
    float* bufB = (float*)w;                 w += (size_t)N * DD * sizeof(float);
    float* bufC = (float*)w;                 w += (size_t)N * DD * sizeof(float);
    int* deg     = (int*)w;                  w += (size_t)N * sizeof(int);
    int* fill    = (int*)w;                  w += (size_t)N * sizeof(int);
    int* row_ptr = (int*)w;                  w += (size_t)(N + 1) * sizeof(int);
    int* colidx  = (int*)w;                  w += (size_t)NNZ * sizeof(int);
    float* wnorm = (float*)w;                w += (size_t)NNZ * sizeof(float);
    float* dinv  = (float*)w;                w += (size_t)N * sizeof(float);
    int* bsum    = (int*)w;                  w += 512 * sizeof(int);
    int* boff    = (int*)w;                  w += 512 * sizeof(int);
    float* ss    = (float*)w;                w += 256 * sizeof(float);
    unsigned short* wb = (unsigned short*)w; w += 16384 * sizeof(unsigned short);
    float* partials = (float*)w;             w += 256 * 256 * sizeof(float);

    const int NB = (N + 1 + 255) / 256;      // scan blocks
    const int STATS_GRID = 256;

    // ---- CSR build ----
    k_init<<<(N + 255) / 256, 256, 0, stream>>>(deg, fill, N);
    k_hist<<<(E + 255) / 256, 256, 0, stream>>>(ei, E, deg);
    k_dinv<<<(N + 255) / 256, 256, 0, stream>>>(deg, dinv, N);
    k_scan_a<<<NB, 256, 0, stream>>>(deg, row_ptr, bsum, N);
    k_scan_b<<<1, 512, 0, stream>>>(bsum, boff, NB);
    k_scan_c<<<(N + 1 + 255) / 256, 256, 0, stream>>>(row_ptr, boff, N + 1);
    k_fill<<<(NNZ + 255) / 256, 256, 0, stream>>>(ei, E, N, row_ptr, dinv, fill, colidx, wnorm);

    int gemmGrid = (N + 63) / 64;
    dim3 aggGrid((N + 7) / 8);
    dim3 aggBlk(64, 4);
    dim3 postGrid((N + 3) / 4);
    dim3 postBlk(64, 4);
    float inv_n = 1.0f / (float)N;
    int outGrid = (N + 511) / 512;

    // ---- layer 1 ----
    k_wrepack<<<8, 256, 0, stream>>>(W1, wb);
    k_gemm_mfma<<<gemmGrid, 256, 0, stream>>>(x, wb, bufB, N);
    k_agg<<<aggGrid, aggBlk, 0, stream>>>(bufB, row_ptr, colidx, wnorm, dinv, b1, bufA, N);
    k_bnstats<<<STATS_GRID, 256, 0, stream>>>(bufA, N, partials);
    k_bnfinal<<<1, 128, 0, stream>>>(partials, g1, be1, ss, inv_n, STATS_GRID);
    k_post<<<postGrid, postBlk, 0, stream>>>(bufA, ss, nullptr, bufA, N);   // h1 in bufA

    // ---- layer 2 ----
    k_wrepack<<<8, 256, 0, stream>>>(W2, wb);
    k_gemm_mfma<<<gemmGrid, 256, 0, stream>>>(bufA, wb, bufB, N);
    k_agg<<<aggGrid, aggBlk, 0, stream>>>(bufB, row_ptr, colidx, wnorm, dinv, b2, bufC, N);
    k_bnstats<<<STATS_GRID, 256, 0, stream>>>(bufC, N, partials);
    k_bnfinal<<<1, 128, 0, stream>>>(partials, g2, be2, ss, inv_n, STATS_GRID);
    k_post<<<postGrid, postBlk, 0, stream>>>(bufC, ss, bufA, bufC, N);      // h2 in bufC

    // ---- layer 3 ----
    k_wrepack<<<8, 256, 0, stream>>>(W3, wb);
    k_gemm_mfma<<<gemmGrid, 256, 0, stream>>>(bufC, wb, bufB, N);
    k_agg<<<aggGrid, aggBlk, 0, stream>>>(bufB, row_ptr, colidx, wnorm, dinv, b3, bufA, N);
    k_bnstats<<<STATS_GRID, 256, 0, stream>>>(bufA, N, partials);
    k_bnfinal<<<1, 128, 0, stream>>>(partials, g3, be3, ss, inv_n, STATS_GRID);
    k_post<<<postGrid, postBlk, 0, stream>>>(bufA, ss, bufC, bufA, N);      // h3 in bufA

    // ---- output ----
    k_outgemm<<<outGrid, 256, 0, stream>>>(bufA, Wout, bout, out, N);
}

// Round 5
// 575.658 us; speedup vs baseline: 2.3296x; 1.3490x over previous
//
#include <hip/hip_runtime.h>
#include <math.h>

#define DD 128
#define COUT 40
#define BN_EPS 1e-5f
#define L2_EPS 1e-12f

typedef __attribute__((ext_vector_type(8))) short bf16x8;
typedef __attribute__((ext_vector_type(4))) float f32x4;

static __device__ inline unsigned short f2bf(float f) {
    unsigned int x = __float_as_uint(f);
    unsigned int r = (x + 0x7FFFu + ((x >> 16) & 1u)) >> 16;   // RNE
    return (unsigned short)r;
}
static __device__ inline float bf2f(unsigned short u) {
    return __uint_as_float(((unsigned int)u) << 16);
}

// ---------------- setup kernels ----------------

__global__ void k_init(int* deg, int* fill, int n) {
    int i = blockIdx.x * blockDim.x + threadIdx.x;
    if (i < n) { deg[i] = 1; fill[i] = 0; }   // deg starts at 1 (self loop)
}

__global__ void k_hist(const int* ei, int E, int* deg) {
    int i = blockIdx.x * blockDim.x + threadIdx.x;
    if (i < E) atomicAdd(&deg[ei[E + i]], 1);   // dst = ei[E+i]
}

__global__ void k_dinv(const int* deg, float* dinv, int n) {
    int i = blockIdx.x * blockDim.x + threadIdx.x;
    if (i < n) dinv[i] = rsqrtf((float)deg[i]);
}

// exclusive scan over n+1 entries, 3 phases
__global__ void k_scan_a(const int* deg, int* row_ptr, int* bsum, int n) {
    __shared__ int s[256];
    int t = threadIdx.x;
    int idx = blockIdx.x * 256 + t;
    int v = (idx < n) ? deg[idx] : 0;
    s[t] = v; __syncthreads();
    for (int off = 1; off < 256; off <<= 1) {
        int x = (t >= off) ? s[t - off] : 0;
        __syncthreads(); s[t] += x; __syncthreads();
    }
    if (idx <= n) row_ptr[idx] = s[t] - v;     // local exclusive
    if (t == 255) bsum[blockIdx.x] = s[255];
}

__global__ void k_scan_b(const int* bsum, int* boff, int nb) {
    __shared__ int s[512];
    int t = threadIdx.x;
    int v = (t < nb) ? bsum[t] : 0;
    s[t] = v; __syncthreads();
    for (int off = 1; off < 512; off <<= 1) {
        int x = (t >= off) ? s[t - off] : 0;
        __syncthreads(); s[t] += x; __syncthreads();
    }
    if (t < nb) boff[t] = s[t] - v;            // exclusive block offsets
}

__global__ void k_scan_c(int* row_ptr, const int* boff, int n1) {
    int idx = blockIdx.x * blockDim.x + threadIdx.x;
    if (idx < n1) row_ptr[idx] += boff[idx >> 8];
}

__global__ void k_fill(const int* ei, int E, int n, const int* row_ptr,
                       const float* dinv, int* fill, int* colidx, float* wnorm) {
    int i = blockIdx.x * blockDim.x + threadIdx.x;
    int total = E + n;
    if (i >= total) return;
    int u, v;
    if (i < E) { u = ei[i]; v = ei[E + i]; }
    else { u = i - E; v = u; }                 // self loop
    int p = atomicAdd(&fill[v], 1);
    int pos = row_ptr[v] + p;
    colidx[pos] = u;
    wnorm[pos] = dinv[u];
}

// repack W (128x128 fp32, row-major [k][n]) into bf16 B-fragment order:
// out[((kc*8+cc)*64 + lane)*8 + j] = bf16( W[(kc*32 + (lane>>4)*8 + j)*128 + cc*16 + (lane&15)] )
__global__ void k_wrepack(const float* __restrict__ W, unsigned short* __restrict__ out) {
    int idx = blockIdx.x * 256 + threadIdx.x;      // 0..2047
    int kc = idx >> 9;
    int cc = (idx >> 6) & 7;
    int lane = idx & 63;
    int n = cc * 16 + (lane & 15);
    int kb = kc * 32 + (lane >> 4) * 8;
    unsigned short tmp[8];
#pragma unroll
    for (int j = 0; j < 8; j++) tmp[j] = f2bf(W[(size_t)(kb + j) * DD + n]);
    uint4* dst = (uint4*)&out[(size_t)idx * 8];
    *dst = *(const uint4*)tmp;
}

// ---------------- compute kernels ----------------

// C(bf16) = A(nrows x 128) @ W(128x128), MFMA bf16. Block = 4 waves, 64 rows.
// A read either fp32 (+convert) or bf16 direct, per template flag.
template <bool BF16IN>
__global__ __launch_bounds__(256) void k_gemm_mfma(const void* __restrict__ Ap,
                                                   const unsigned short* __restrict__ Wb,
                                                   unsigned short* __restrict__ C, int nrows) {
    __shared__ __align__(16) unsigned short Ws[16384];   // 32 KB
    const int tid = threadIdx.x;
    for (int i = tid; i < 2048; i += 256)
        ((uint4*)Ws)[i] = ((const uint4*)Wb)[i];
    __syncthreads();

    const int wv = tid >> 6;
    const int lane = tid & 63;
    const int R0 = blockIdx.x * 64 + wv * 16;
    if (R0 >= nrows) return;
    const int m = lane & 15, q = lane >> 4;

    int rr = R0 + m; if (rr >= nrows) rr = nrows - 1;

    bf16x8 af[4];
    if (BF16IN) {
        const unsigned short* Ar = (const unsigned short*)Ap + (size_t)rr * DD + q * 8;
#pragma unroll
        for (int kc = 0; kc < 4; kc++)
            af[kc] = *(const bf16x8*)(Ar + kc * 32);
    } else {
        const float* Ar = (const float*)Ap + (size_t)rr * DD + q * 8;
#pragma unroll
        for (int kc = 0; kc < 4; kc++) {
            float4 lo = *(const float4*)(Ar + kc * 32);
            float4 hi = *(const float4*)(Ar + kc * 32 + 4);
            unsigned short t[8];
            t[0] = f2bf(lo.x); t[1] = f2bf(lo.y); t[2] = f2bf(lo.z); t[3] = f2bf(lo.w);
            t[4] = f2bf(hi.x); t[5] = f2bf(hi.y); t[6] = f2bf(hi.z); t[7] = f2bf(hi.w);
            af[kc] = *(const bf16x8*)t;
        }
    }

    f32x4 acc[8];
#pragma unroll
    for (int cc = 0; cc < 8; cc++) acc[cc] = (f32x4){0.f, 0.f, 0.f, 0.f};

#pragma unroll
    for (int kc = 0; kc < 4; kc++) {
#pragma unroll
        for (int cc = 0; cc < 8; cc++) {
            bf16x8 b = *(const bf16x8*)&Ws[(size_t)((kc * 8 + cc) * 64 + lane) * 8];
            acc[cc] = __builtin_amdgcn_mfma_f32_16x16x32_bf16(af[kc], b, acc[cc], 0, 0, 0);
        }
    }

    // C/D layout: col = lane&15 (=m), row = q*4 + reg
#pragma unroll
    for (int cc = 0; cc < 8; cc++) {
#pragma unroll
        for (int i = 0; i < 4; i++) {
            int r = R0 + q * 4 + i;
            if (r < nrows) C[(size_t)r * DD + cc * 16 + m] = f2bf(acc[cc][i]);
        }
    }
}

// out[v] = bias + dv * sum_j wnorm[j] * lin_bf16[col[j]]; 2 nodes per wave
__global__ void k_agg(const unsigned short* __restrict__ lin, const int* __restrict__ row_ptr,
                      const int* __restrict__ colidx, const float* __restrict__ wnorm,
                      const float* __restrict__ dinv, const float* __restrict__ bias,
                      float* __restrict__ out, int n) {
    int lane = threadIdx.x;
    int half = lane >> 5;
    int li = lane & 31;
    int v = blockIdx.x * 8 + threadIdx.y * 2 + half;
    if (v >= n) return;
    int c = li * 4;
    int s = row_ptr[v], e = row_ptr[v + 1];
    float dv = dinv[v];
    float4 accA = *(const float4*)&bias[c];
    float4 accB = make_float4(0.f, 0.f, 0.f, 0.f);
    int j = s;
    for (; j + 1 < e; j += 2) {
        int u0 = colidx[j], u1 = colidx[j + 1];
        float w0 = dv * wnorm[j];
        float w1 = dv * wnorm[j + 1];
        ushort4 t0 = *(const ushort4*)&lin[(size_t)u0 * DD + c];
        ushort4 t1 = *(const ushort4*)&lin[(size_t)u1 * DD + c];
        accA.x += w0 * bf2f(t0.x); accA.y += w0 * bf2f(t0.y);
        accA.z += w0 * bf2f(t0.z); accA.w += w0 * bf2f(t0.w);
        accB.x += w1 * bf2f(t1.x); accB.y += w1 * bf2f(t1.y);
        accB.z += w1 * bf2f(t1.z); accB.w += w1 * bf2f(t1.w);
    }
    if (j < e) {
        int u = colidx[j];
        float w = dv * wnorm[j];
        ushort4 t = *(const ushort4*)&lin[(size_t)u * DD + c];
        accA.x += w * bf2f(t.x); accA.y += w * bf2f(t.y);
        accA.z += w * bf2f(t.z); accA.w += w * bf2f(t.w);
    }
    accA.x += accB.x; accA.y += accB.y; accA.z += accB.z; accA.w += accB.w;
    *(float4*)&out[(size_t)v * DD + c] = accA;
}

__global__ void k_zero(float* p, int n) {
    int i = blockIdx.x * blockDim.x + threadIdx.x;
    if (i < n) p[i] = 0.f;
}

// stats[0..127] += col sums, stats[128..255] += col sumsq (LDS-reduced per block)
__global__ __launch_bounds__(256) void k_bnstats(const float* __restrict__ X, int n,
                                                 float* __restrict__ stats) {
    int cg = (threadIdx.x & 31) * 4;
    int rg = threadIdx.x >> 5;
    float s0 = 0, s1 = 0, s2 = 0, s3 = 0;
    float q0 = 0, q1 = 0, q2 = 0, q3 = 0;
    for (int r = blockIdx.x * 8 + rg; r < n; r += gridDim.x * 8) {
        float4 x = *(const float4*)&X[(size_t)r * DD + cg];
        s0 += x.x; s1 += x.y; s2 += x.z; s3 += x.w;
        q0 += x.x * x.x; q1 += x.y * x.y; q2 += x.z * x.z; q3 += x.w * x.w;
    }
    __shared__ float sh[8][128];
    __shared__ float qh[8][128];
    sh[rg][cg] = s0; sh[rg][cg + 1] = s1; sh[rg][cg + 2] = s2; sh[rg][cg + 3] = s3;
    qh[rg][cg] = q0; qh[rg][cg + 1] = q1; qh[rg][cg + 2] = q2; qh[rg][cg + 3] = q3;
    __syncthreads();
    if (threadIdx.x < 128) {
        float a = 0, b = 0;
        for (int g = 0; g < 8; g++) { a += sh[g][threadIdx.x]; b += qh[g][threadIdx.x]; }
        atomicAdd(&stats[threadIdx.x], a);
        atomicAdd(&stats[128 + threadIdx.x], b);
    }
}

__global__ void k_bnfinal(const float* __restrict__ stats, const float* g,
                          const float* be, float* ss, float inv_n) {
    int c = threadIdx.x;
    float mu = stats[c] * inv_n;
    float var = stats[128 + c] * inv_n - mu * mu;
    float sc = g[c] * rsqrtf(var + BN_EPS);
    ss[c] = sc;
    ss[128 + c] = be[c] - mu * sc;
}

// y = relu(x*scale+shift) (+res); row L2 normalize. One wave per node.
// Writes fp32 out and (optionally) a bf16 copy for the next GEMM's A operand.
__global__ void k_post(const float* __restrict__ X, const float* __restrict__ ss,
                       const float* __restrict__ res, float* __restrict__ out,
                       unsigned short* __restrict__ out_bf, int n) {
    int v = blockIdx.x * blockDim.y + threadIdx.y;
    if (v >= n) return;
    int lane = threadIdx.x;
    int c = lane * 2;
    float2 x = *(const float2*)&X[(size_t)v * DD + c];
    float y0 = fmaxf(x.x * ss[c] + ss[128 + c], 0.f);
    float y1 = fmaxf(x.y * ss[c + 1] + ss[128 + c + 1], 0.f);
    if (res) {
        float2 r = *(const float2*)&res[(size_t)v * DD + c];
        y0 += r.x; y1 += r.y;
    }
    float sum = y0 * y0 + y1 * y1;
    for (int m = 1; m < 64; m <<= 1) sum += __shfl_xor(sum, m, 64);
    float inv = 1.f / fmaxf(sqrtf(sum), L2_EPS);
    y0 *= inv; y1 *= inv;
    *(float2*)&out[(size_t)v * DD + c] = make_float2(y0, y1);
    if (out_bf) {
        ushort2 p; p.x = f2bf(y0); p.y = f2bf(y1);
        *(ushort2*)&out_bf[(size_t)v * DD + c] = p;
    }
}

// logits = h @ Wout + bout;  Wout: 128x40. 2 rows/thread, uniform LDS B reads.
__global__ __launch_bounds__(256) void k_outgemm(const float* __restrict__ A,
                                                 const float* __restrict__ W,
                                                 const float* __restrict__ b,
                                                 float* __restrict__ C, int n) {
    __shared__ float Wl[128 * COUT];   // 20 KB
    int t = threadIdx.x;
    for (int i = t; i < 128 * COUT / 4; i += 256)
        *(float4*)&Wl[i * 4] = *(const float4*)&W[i * 4];
    __syncthreads();
    int stride = gridDim.x * 256;
    int r0 = blockIdx.x * 256 + t;
    int r1 = r0 + stride;
    float acc0[COUT], acc1[COUT];
#pragma unroll
    for (int c = 0; c < COUT; c++) { acc0[c] = b[c]; acc1[c] = b[c]; }
    bool h0 = r0 < n, h1 = r1 < n;
    const float* A0 = A + (size_t)(h0 ? r0 : 0) * DD;
    const float* A1 = A + (size_t)(h1 ? r1 : 0) * DD;
    for (int k0 = 0; k0 < 128; k0 += 4) {
        float4 a0 = *(const float4*)(A0 + k0);
        float4 a1 = *(const float4*)(A1 + k0);
        float av0[4] = {a0.x, a0.y, a0.z, a0.w};
        float av1[4] = {a1.x, a1.y, a1.z, a1.w};
#pragma unroll
        for (int kk = 0; kk < 4; kk++) {
            const float* wr = &Wl[(k0 + kk) * COUT];
#pragma unroll
            for (int c = 0; c < COUT; c++) {
                acc0[c] += av0[kk] * wr[c];
                acc1[c] += av1[kk] * wr[c];
            }
        }
    }
    if (h0) {
        float* Cr = C + (size_t)r0 * COUT;
#pragma unroll
        for (int c4 = 0; c4 < COUT / 4; c4++)
            *(float4*)&Cr[c4 * 4] = make_float4(acc0[c4 * 4], acc0[c4 * 4 + 1],
                                                acc0[c4 * 4 + 2], acc0[c4 * 4 + 3]);
    }
    if (h1) {
        float* Cr = C + (size_t)r1 * COUT;
#pragma unroll
        for (int c4 = 0; c4 < COUT / 4; c4++)
            *(float4*)&Cr[c4 * 4] = make_float4(acc1[c4 * 4], acc1[c4 * 4 + 1],
                                                acc1[c4 * 4 + 2], acc1[c4 * 4 + 3]);
    }
}

// ---------------- host ----------------

extern "C" void kernel_launch(void* const* d_in, const int* in_sizes, int n_in,
                              void* d_out, int out_size, void* d_ws, size_t ws_size,
                              hipStream_t stream) {
    const float* x    = (const float*)d_in[0];
    const int*   ei   = (const int*)d_in[1];
    const float* W1   = (const float*)d_in[2];
    const float* b1   = (const float*)d_in[3];
    const float* W2   = (const float*)d_in[4];
    const float* b2   = (const float*)d_in[5];
    const float* W3   = (const float*)d_in[6];
    const float* b3   = (const float*)d_in[7];
    const float* g1   = (const float*)d_in[8];
    const float* be1  = (const float*)d_in[9];
    const float* g2   = (const float*)d_in[10];
    const float* be2  = (const float*)d_in[11];
    const float* g3   = (const float*)d_in[12];
    const float* be3  = (const float*)d_in[13];
    const float* Wout = (const float*)d_in[14];
    const float* bout = (const float*)d_in[15];
    float* out = (float*)d_out;

    const int N = in_sizes[0] / DD;
    const int E = in_sizes[1] / 2;
    const int NNZ = E + N;

    // workspace layout (16B-aligned chunks first)
    char* w = (char*)d_ws;
    float* bufA = (float*)w;                   w += (size_t)N * DD * sizeof(float);
    float* bufC = (float*)w;                   w += (size_t)N * DD * sizeof(float);
    unsigned short* linb = (unsigned short*)w; w += (size_t)N * DD * sizeof(unsigned short);
    unsigned short* hbf  = (unsigned short*)w; w += (size_t)N * DD * sizeof(unsigned short);
    unsigned short* wb   = (unsigned short*)w; w += 16384 * sizeof(unsigned short);
    int* deg     = (int*)w;                    w += (size_t)N * sizeof(int);
    int* fill    = (int*)w;                    w += (size_t)N * sizeof(int);
    int* row_ptr = (int*)w;                    w += (size_t)(N + 1) * sizeof(int);
    int* colidx  = (int*)w;                    w += (size_t)NNZ * sizeof(int);
    float* wnorm = (float*)w;                  w += (size_t)NNZ * sizeof(float);
    float* dinv  = (float*)w;                  w += (size_t)N * sizeof(float);
    int* bsum    = (int*)w;                    w += 512 * sizeof(int);
    int* boff    = (int*)w;                    w += 512 * sizeof(int);
    float* stats = (float*)w;                  w += 256 * sizeof(float);
    float* ss    = (float*)w;                  w += 256 * sizeof(float);

    const int NB = (N + 1 + 255) / 256;      // scan blocks
    const int STATS_GRID = 128;

    // ---- CSR build ----
    k_init<<<(N + 255) / 256, 256, 0, stream>>>(deg, fill, N);
    k_hist<<<(E + 255) / 256, 256, 0, stream>>>(ei, E, deg);
    k_dinv<<<(N + 255) / 256, 256, 0, stream>>>(deg, dinv, N);
    k_scan_a<<<NB, 256, 0, stream>>>(deg, row_ptr, bsum, N);
    k_scan_b<<<1, 512, 0, stream>>>(bsum, boff, NB);
    k_scan_c<<<(N + 1 + 255) / 256, 256, 0, stream>>>(row_ptr, boff, N + 1);
    k_fill<<<(NNZ + 255) / 256, 256, 0, stream>>>(ei, E, N, row_ptr, dinv, fill, colidx, wnorm);

    int gemmGrid = (N + 63) / 64;
    dim3 aggGrid((N + 7) / 8);
    dim3 aggBlk(64, 4);
    dim3 postGrid((N + 3) / 4);
    dim3 postBlk(64, 4);
    float inv_n = 1.0f / (float)N;
    int outGrid = (N + 511) / 512;

    // ---- layer 1 ----
    k_wrepack<<<8, 256, 0, stream>>>(W1, wb);
    k_gemm_mfma<false><<<gemmGrid, 256, 0, stream>>>(x, wb, linb, N);
    k_agg<<<aggGrid, aggBlk, 0, stream>>>(linb, row_ptr, colidx, wnorm, dinv, b1, bufA, N);
    k_zero<<<1, 256, 0, stream>>>(stats, 256);
    k_bnstats<<<STATS_GRID, 256, 0, stream>>>(bufA, N, stats);
    k_bnfinal<<<1, 128, 0, stream>>>(stats, g1, be1, ss, inv_n);
    k_post<<<postGrid, postBlk, 0, stream>>>(bufA, ss, nullptr, bufA, hbf, N);  // h1: bufA + hbf

    // ---- layer 2 ----
    k_wrepack<<<8, 256, 0, stream>>>(W2, wb);
    k_gemm_mfma<true><<<gemmGrid, 256, 0, stream>>>(hbf, wb, linb, N);
    k_agg<<<aggGrid, aggBlk, 0, stream>>>(linb, row_ptr, colidx, wnorm, dinv, b2, bufC, N);
    k_zero<<<1, 256, 0, stream>>>(stats, 256);
    k_bnstats<<<STATS_GRID, 256, 0, stream>>>(bufC, N, stats);
    k_bnfinal<<<1, 128, 0, stream>>>(stats, g2, be2, ss, inv_n);
    k_post<<<postGrid, postBlk, 0, stream>>>(bufC, ss, bufA, bufC, hbf, N);     // h2: bufC + hbf

    // ---- layer 3 ----
    k_wrepack<<<8, 256, 0, stream>>>(W3, wb);
    k_gemm_mfma<true><<<gemmGrid, 256, 0, stream>>>(hbf, wb, linb, N);
    k_agg<<<aggGrid, aggBlk, 0, stream>>>(linb, row_ptr, colidx, wnorm, dinv, b3, bufA, N);
    k_zero<<<1, 256, 0, stream>>>(stats, 256);
    k_bnstats<<<STATS_GRID, 256, 0, stream>>>(bufA, N, stats);
    k_bnfinal<<<1, 128, 0, stream>>>(stats, g3, be3, ss, inv_n);
    k_post<<<postGrid, postBlk, 0, stream>>>(bufA, ss, bufC, bufA, nullptr, N); // h3 in bufA

    // ---- output ----
    k_outgemm<<<outGrid, 256, 0, stream>>>(bufA, Wout, bout, out, N);
}

// Round 6
// 546.848 us; speedup vs baseline: 2.4523x; 1.0527x over previous
//
#include <hip/hip_runtime.h>
#include <math.h>

#define DD 128
#define COUT 40
#define BN_EPS 1e-5f
#define L2_EPS 1e-12f

typedef __attribute__((ext_vector_type(8))) short bf16x8;
typedef __attribute__((ext_vector_type(4))) float f32x4;

static __device__ inline unsigned short f2bf(float f) {
    unsigned int x = __float_as_uint(f);
    unsigned int r = (x + 0x7FFFu + ((x >> 16) & 1u)) >> 16;   // RNE
    return (unsigned short)r;
}
static __device__ inline float bf2f(unsigned short u) {
    return __uint_as_float(((unsigned int)u) << 16);
}

// ---------------- setup kernels ----------------

__global__ void k_init(int* deg, int* fill, int n) {
    int i = blockIdx.x * blockDim.x + threadIdx.x;
    if (i < n) { deg[i] = 1; fill[i] = 0; }   // deg starts at 1 (self loop)
}

__global__ void k_hist(const int* ei, int E, int* deg) {
    int i = blockIdx.x * blockDim.x + threadIdx.x;
    if (i < E) atomicAdd(&deg[ei[E + i]], 1);   // dst = ei[E+i]
}

__global__ void k_dinv(const int* deg, float* dinv, int n) {
    int i = blockIdx.x * blockDim.x + threadIdx.x;
    if (i < n) dinv[i] = rsqrtf((float)deg[i]);
}

// exclusive scan over n+1 entries, 3 phases
__global__ void k_scan_a(const int* deg, int* row_ptr, int* bsum, int n) {
    __shared__ int s[256];
    int t = threadIdx.x;
    int idx = blockIdx.x * 256 + t;
    int v = (idx < n) ? deg[idx] : 0;
    s[t] = v; __syncthreads();
    for (int off = 1; off < 256; off <<= 1) {
        int x = (t >= off) ? s[t - off] : 0;
        __syncthreads(); s[t] += x; __syncthreads();
    }
    if (idx <= n) row_ptr[idx] = s[t] - v;     // local exclusive
    if (t == 255) bsum[blockIdx.x] = s[255];
}

__global__ void k_scan_b(const int* bsum, int* boff, int nb) {
    __shared__ int s[512];
    int t = threadIdx.x;
    int v = (t < nb) ? bsum[t] : 0;
    s[t] = v; __syncthreads();
    for (int off = 1; off < 512; off <<= 1) {
        int x = (t >= off) ? s[t - off] : 0;
        __syncthreads(); s[t] += x; __syncthreads();
    }
    if (t < nb) boff[t] = s[t] - v;            // exclusive block offsets
}

__global__ void k_scan_c(int* row_ptr, const int* boff, int n1) {
    int idx = blockIdx.x * blockDim.x + threadIdx.x;
    if (idx < n1) row_ptr[idx] += boff[idx >> 8];
}

// single 8B store per edge: epair[pos] = {src, bits(dinv[src])}
__global__ void k_fill(const int* ei, int E, int n, const int* row_ptr,
                       const float* dinv, int* fill, int2* epair) {
    int i = blockIdx.x * blockDim.x + threadIdx.x;
    int total = E + n;
    if (i >= total) return;
    int u, v;
    if (i < E) { u = ei[i]; v = ei[E + i]; }
    else { u = i - E; v = u; }                 // self loop
    int p = atomicAdd(&fill[v], 1);
    int pos = row_ptr[v] + p;
    int2 pr; pr.x = u; pr.y = __float_as_int(dinv[u]);
    epair[pos] = pr;
}

// repack W (128x128 fp32, row-major [k][n]) into bf16 B-fragment order; block 0 zeros stats.
__global__ void k_wrepack(const float* __restrict__ W, unsigned short* __restrict__ out,
                          float* __restrict__ stats) {
    if (blockIdx.x == 0) stats[threadIdx.x] = 0.f;
    int idx = blockIdx.x * 256 + threadIdx.x;      // 0..2047
    int kc = idx >> 9;
    int cc = (idx >> 6) & 7;
    int lane = idx & 63;
    int n = cc * 16 + (lane & 15);
    int kb = kc * 32 + (lane >> 4) * 8;
    unsigned short tmp[8];
#pragma unroll
    for (int j = 0; j < 8; j++) tmp[j] = f2bf(W[(size_t)(kb + j) * DD + n]);
    uint4* dst = (uint4*)&out[(size_t)idx * 8];
    *dst = *(const uint4*)tmp;
}

// repack Wout (128x40 fp32) into bf16 B-frag order, N padded to 48 (3 cc-tiles)
__global__ void k_wrepack_out(const float* __restrict__ W, unsigned short* __restrict__ out) {
    int idx = blockIdx.x * 256 + threadIdx.x;      // 0..767
    if (idx >= 768) return;
    int kc = idx / 192;
    int rem = idx % 192;
    int cc = rem >> 6;
    int lane = rem & 63;
    int n = cc * 16 + (lane & 15);
    int kb = kc * 32 + (lane >> 4) * 8;
    unsigned short tmp[8];
#pragma unroll
    for (int j = 0; j < 8; j++)
        tmp[j] = (n < COUT) ? f2bf(W[(size_t)(kb + j) * COUT + n]) : 0;
    uint4* dst = (uint4*)&out[(size_t)idx * 8];
    *dst = *(const uint4*)tmp;
}

// ---------------- compute kernels ----------------

// C(bf16) = A(nrows x 128) @ W(128x128), MFMA bf16. Block = 4 waves, 64 rows.
template <bool BF16IN>
__global__ __launch_bounds__(256) void k_gemm_mfma(const void* __restrict__ Ap,
                                                   const unsigned short* __restrict__ Wb,
                                                   unsigned short* __restrict__ C, int nrows) {
    __shared__ __align__(16) unsigned short Ws[16384];   // 32 KB
    const int tid = threadIdx.x;
    for (int i = tid; i < 2048; i += 256)
        ((uint4*)Ws)[i] = ((const uint4*)Wb)[i];
    __syncthreads();

    const int wv = tid >> 6;
    const int lane = tid & 63;
    const int R0 = blockIdx.x * 64 + wv * 16;
    if (R0 >= nrows) return;
    const int m = lane & 15, q = lane >> 4;

    int rr = R0 + m; if (rr >= nrows) rr = nrows - 1;

    bf16x8 af[4];
    if (BF16IN) {
        const unsigned short* Ar = (const unsigned short*)Ap + (size_t)rr * DD + q * 8;
#pragma unroll
        for (int kc = 0; kc < 4; kc++)
            af[kc] = *(const bf16x8*)(Ar + kc * 32);
    } else {
        const float* Ar = (const float*)Ap + (size_t)rr * DD + q * 8;
#pragma unroll
        for (int kc = 0; kc < 4; kc++) {
            float4 lo = *(const float4*)(Ar + kc * 32);
            float4 hi = *(const float4*)(Ar + kc * 32 + 4);
            unsigned short t[8];
            t[0] = f2bf(lo.x); t[1] = f2bf(lo.y); t[2] = f2bf(lo.z); t[3] = f2bf(lo.w);
            t[4] = f2bf(hi.x); t[5] = f2bf(hi.y); t[6] = f2bf(hi.z); t[7] = f2bf(hi.w);
            af[kc] = *(const bf16x8*)t;
        }
    }

    f32x4 acc[8];
#pragma unroll
    for (int cc = 0; cc < 8; cc++) acc[cc] = (f32x4){0.f, 0.f, 0.f, 0.f};

#pragma unroll
    for (int kc = 0; kc < 4; kc++) {
#pragma unroll
        for (int cc = 0; cc < 8; cc++) {
            bf16x8 b = *(const bf16x8*)&Ws[(size_t)((kc * 8 + cc) * 64 + lane) * 8];
            acc[cc] = __builtin_amdgcn_mfma_f32_16x16x32_bf16(af[kc], b, acc[cc], 0, 0, 0);
        }
    }

    // C/D layout: col = lane&15 (=m), row = q*4 + reg
#pragma unroll
    for (int cc = 0; cc < 8; cc++) {
#pragma unroll
        for (int i = 0; i < 4; i++) {
            int r = R0 + q * 4 + i;
            if (r < nrows) C[(size_t)r * DD + cc * 16 + m] = f2bf(acc[cc][i]);
        }
    }
}

// out[v] = bias + dv * sum_j w_j * lin_bf16[u_j]; 2 nodes per wave; epair = {u, bits(dinv_u)}
__global__ void k_agg(const unsigned short* __restrict__ lin, const int* __restrict__ row_ptr,
                      const int2* __restrict__ epair, const float* __restrict__ dinv,
                      const float* __restrict__ bias, float* __restrict__ out, int n) {
    int lane = threadIdx.x;
    int half = lane >> 5;
    int li = lane & 31;
    int v = blockIdx.x * 8 + threadIdx.y * 2 + half;
    if (v >= n) return;
    int c = li * 4;
    int s = row_ptr[v], e = row_ptr[v + 1];
    float dv = dinv[v];
    float4 accA = *(const float4*)&bias[c];
    float4 accB = make_float4(0.f, 0.f, 0.f, 0.f);
    int j = s;
    for (; j + 1 < e; j += 2) {
        int2 p0 = epair[j], p1 = epair[j + 1];
        float w0 = dv * __int_as_float(p0.y);
        float w1 = dv * __int_as_float(p1.y);
        ushort4 t0 = *(const ushort4*)&lin[(size_t)p0.x * DD + c];
        ushort4 t1 = *(const ushort4*)&lin[(size_t)p1.x * DD + c];
        accA.x += w0 * bf2f(t0.x); accA.y += w0 * bf2f(t0.y);
        accA.z += w0 * bf2f(t0.z); accA.w += w0 * bf2f(t0.w);
        accB.x += w1 * bf2f(t1.x); accB.y += w1 * bf2f(t1.y);
        accB.z += w1 * bf2f(t1.z); accB.w += w1 * bf2f(t1.w);
    }
    if (j < e) {
        int2 p = epair[j];
        float w = dv * __int_as_float(p.y);
        ushort4 t = *(const ushort4*)&lin[(size_t)p.x * DD + c];
        accA.x += w * bf2f(t.x); accA.y += w * bf2f(t.y);
        accA.z += w * bf2f(t.z); accA.w += w * bf2f(t.w);
    }
    accA.x += accB.x; accA.y += accB.y; accA.z += accB.z; accA.w += accB.w;
    *(float4*)&out[(size_t)v * DD + c] = accA;
}

// stats[0..127] += col sums, stats[128..255] += col sumsq (LDS-reduced per block)
__global__ __launch_bounds__(256) void k_bnstats(const float* __restrict__ X, int n,
                                                 float* __restrict__ stats) {
    int cg = (threadIdx.x & 31) * 4;
    int rg = threadIdx.x >> 5;
    float s0 = 0, s1 = 0, s2 = 0, s3 = 0;
    float q0 = 0, q1 = 0, q2 = 0, q3 = 0;
    for (int r = blockIdx.x * 8 + rg; r < n; r += gridDim.x * 8) {
        float4 x = *(const float4*)&X[(size_t)r * DD + cg];
        s0 += x.x; s1 += x.y; s2 += x.z; s3 += x.w;
        q0 += x.x * x.x; q1 += x.y * x.y; q2 += x.z * x.z; q3 += x.w * x.w;
    }
    __shared__ float sh[8][128];
    __shared__ float qh[8][128];
    sh[rg][cg] = s0; sh[rg][cg + 1] = s1; sh[rg][cg + 2] = s2; sh[rg][cg + 3] = s3;
    qh[rg][cg] = q0; qh[rg][cg + 1] = q1; qh[rg][cg + 2] = q2; qh[rg][cg + 3] = q3;
    __syncthreads();
    if (threadIdx.x < 128) {
        float a = 0, b = 0;
        for (int g = 0; g < 8; g++) { a += sh[g][threadIdx.x]; b += qh[g][threadIdx.x]; }
        atomicAdd(&stats[threadIdx.x], a);
        atomicAdd(&stats[128 + threadIdx.x], b);
    }
}

__global__ void k_bnfinal(const float* __restrict__ stats, const float* g,
                          const float* be, float* ss, float inv_n) {
    int c = threadIdx.x;
    float mu = stats[c] * inv_n;
    float var = stats[128 + c] * inv_n - mu * mu;
    float sc = g[c] * rsqrtf(var + BN_EPS);
    ss[c] = sc;
    ss[128 + c] = be[c] - mu * sc;
}

// y = relu(x*scale+shift) (+res); row L2 normalize. One wave per node.
// Writes fp32 out and (optionally) a bf16 copy for downstream MFMA A operands.
__global__ void k_post(const float* __restrict__ X, const float* __restrict__ ss,
                       const float* __restrict__ res, float* __restrict__ out,
                       unsigned short* __restrict__ out_bf, int n) {
    int v = blockIdx.x * blockDim.y + threadIdx.y;
    if (v >= n) return;
    int lane = threadIdx.x;
    int c = lane * 2;
    float2 x = *(const float2*)&X[(size_t)v * DD + c];
    float y0 = fmaxf(x.x * ss[c] + ss[128 + c], 0.f);
    float y1 = fmaxf(x.y * ss[c + 1] + ss[128 + c + 1], 0.f);
    if (res) {
        float2 r = *(const float2*)&res[(size_t)v * DD + c];
        y0 += r.x; y1 += r.y;
    }
    float sum = y0 * y0 + y1 * y1;
    for (int m = 1; m < 64; m <<= 1) sum += __shfl_xor(sum, m, 64);
    float inv = 1.f / fmaxf(sqrtf(sum), L2_EPS);
    y0 *= inv; y1 *= inv;
    *(float2*)&out[(size_t)v * DD + c] = make_float2(y0, y1);
    if (out_bf) {
        ushort2 p; p.x = f2bf(y0); p.y = f2bf(y1);
        *(ushort2*)&out_bf[(size_t)v * DD + c] = p;
    }
}

// logits = h3(bf16) @ Wout + bout via MFMA; N padded to 48 (3 cc-tiles of 16)
__global__ __launch_bounds__(256) void k_outgemm_mfma(const unsigned short* __restrict__ hbf,
                                                      const unsigned short* __restrict__ wob,
                                                      const float* __restrict__ bout,
                                                      float* __restrict__ C, int n) {
    __shared__ __align__(16) unsigned short Ws[6144];   // 12 KB
    const int tid = threadIdx.x;
    for (int i = tid; i < 768; i += 256)
        ((uint4*)Ws)[i] = ((const uint4*)wob)[i];
    __syncthreads();

    const int wv = tid >> 6;
    const int lane = tid & 63;
    const int R0 = blockIdx.x * 64 + wv * 16;
    if (R0 >= n) return;
    const int m = lane & 15, q = lane >> 4;

    int rr = R0 + m; if (rr >= n) rr = n - 1;
    const unsigned short* Ar = hbf + (size_t)rr * DD + q * 8;

    bf16x8 af[4];
#pragma unroll
    for (int kc = 0; kc < 4; kc++) af[kc] = *(const bf16x8*)(Ar + kc * 32);

    f32x4 acc[3];
#pragma unroll
    for (int cc = 0; cc < 3; cc++) acc[cc] = (f32x4){0.f, 0.f, 0.f, 0.f};

#pragma unroll
    for (int kc = 0; kc < 4; kc++) {
#pragma unroll
        for (int cc = 0; cc < 3; cc++) {
            bf16x8 b = *(const bf16x8*)&Ws[(size_t)((kc * 3 + cc) * 64 + lane) * 8];
            acc[cc] = __builtin_amdgcn_mfma_f32_16x16x32_bf16(af[kc], b, acc[cc], 0, 0, 0);
        }
    }

#pragma unroll
    for (int cc = 0; cc < 3; cc++) {
        int col = cc * 16 + m;
        if (col < COUT) {
            float bb = bout[col];
#pragma unroll
            for (int i = 0; i < 4; i++) {
                int r = R0 + q * 4 + i;
                if (r < n) C[(size_t)r * COUT + col] = acc[cc][i] + bb;
            }
        }
    }
}

// ---------------- host ----------------

extern "C" void kernel_launch(void* const* d_in, const int* in_sizes, int n_in,
                              void* d_out, int out_size, void* d_ws, size_t ws_size,
                              hipStream_t stream) {
    const float* x    = (const float*)d_in[0];
    const int*   ei   = (const int*)d_in[1];
    const float* W1   = (const float*)d_in[2];
    const float* b1   = (const float*)d_in[3];
    const float* W2   = (const float*)d_in[4];
    const float* b2   = (const float*)d_in[5];
    const float* W3   = (const float*)d_in[6];
    const float* b3   = (const float*)d_in[7];
    const float* g1   = (const float*)d_in[8];
    const float* be1  = (const float*)d_in[9];
    const float* g2   = (const float*)d_in[10];
    const float* be2  = (const float*)d_in[11];
    const float* g3   = (const float*)d_in[12];
    const float* be3  = (const float*)d_in[13];
    const float* Wout = (const float*)d_in[14];
    const float* bout = (const float*)d_in[15];
    float* out = (float*)d_out;

    const int N = in_sizes[0] / DD;
    const int E = in_sizes[1] / 2;
    const int NNZ = E + N;

    // workspace layout
    char* w = (char*)d_ws;
    float* bufA = (float*)w;                   w += (size_t)N * DD * sizeof(float);
    float* bufC = (float*)w;                   w += (size_t)N * DD * sizeof(float);
    unsigned short* linb = (unsigned short*)w; w += (size_t)N * DD * sizeof(unsigned short);
    unsigned short* hbf  = (unsigned short*)w; w += (size_t)N * DD * sizeof(unsigned short);
    unsigned short* wb   = (unsigned short*)w; w += 16384 * sizeof(unsigned short);
    unsigned short* wob  = (unsigned short*)w; w += 6144 * sizeof(unsigned short);
    int2* epair  = (int2*)w;                   w += (size_t)NNZ * sizeof(int2);
    int* deg     = (int*)w;                    w += (size_t)N * sizeof(int);
    int* fill    = (int*)w;                    w += (size_t)N * sizeof(int);
    int* row_ptr = (int*)w;                    w += (size_t)(N + 1) * sizeof(int);
    float* dinv  = (float*)w;                  w += (size_t)N * sizeof(float);
    int* bsum    = (int*)w;                    w += 512 * sizeof(int);
    int* boff    = (int*)w;                    w += 512 * sizeof(int);
    float* stats = (float*)w;                  w += 256 * sizeof(float);
    float* ss    = (float*)w;                  w += 256 * sizeof(float);

    const int NB = (N + 1 + 255) / 256;      // scan blocks
    const int STATS_GRID = 128;

    // ---- CSR build ----
    k_init<<<(N + 255) / 256, 256, 0, stream>>>(deg, fill, N);
    k_hist<<<(E + 255) / 256, 256, 0, stream>>>(ei, E, deg);
    k_dinv<<<(N + 255) / 256, 256, 0, stream>>>(deg, dinv, N);
    k_scan_a<<<NB, 256, 0, stream>>>(deg, row_ptr, bsum, N);
    k_scan_b<<<1, 512, 0, stream>>>(bsum, boff, NB);
    k_scan_c<<<(N + 1 + 255) / 256, 256, 0, stream>>>(row_ptr, boff, N + 1);
    k_fill<<<(NNZ + 255) / 256, 256, 0, stream>>>(ei, E, N, row_ptr, dinv, fill, epair);
    k_wrepack_out<<<3, 256, 0, stream>>>(Wout, wob);

    int gemmGrid = (N + 63) / 64;
    dim3 aggGrid((N + 7) / 8);
    dim3 aggBlk(64, 4);
    dim3 postGrid((N + 3) / 4);
    dim3 postBlk(64, 4);
    float inv_n = 1.0f / (float)N;

    // ---- layer 1 ----
    k_wrepack<<<8, 256, 0, stream>>>(W1, wb, stats);
    k_gemm_mfma<false><<<gemmGrid, 256, 0, stream>>>(x, wb, linb, N);
    k_agg<<<aggGrid, aggBlk, 0, stream>>>(linb, row_ptr, epair, dinv, b1, bufA, N);
    k_bnstats<<<STATS_GRID, 256, 0, stream>>>(bufA, N, stats);
    k_bnfinal<<<1, 128, 0, stream>>>(stats, g1, be1, ss, inv_n);
    k_post<<<postGrid, postBlk, 0, stream>>>(bufA, ss, nullptr, bufA, hbf, N);  // h1: bufA + hbf

    // ---- layer 2 ----
    k_wrepack<<<8, 256, 0, stream>>>(W2, wb, stats);
    k_gemm_mfma<true><<<gemmGrid, 256, 0, stream>>>(hbf, wb, linb, N);
    k_agg<<<aggGrid, aggBlk, 0, stream>>>(linb, row_ptr, epair, dinv, b2, bufC, N);
    k_bnstats<<<STATS_GRID, 256, 0, stream>>>(bufC, N, stats);
    k_bnfinal<<<1, 128, 0, stream>>>(stats, g2, be2, ss, inv_n);
    k_post<<<postGrid, postBlk, 0, stream>>>(bufC, ss, bufA, bufC, hbf, N);     // h2: bufC + hbf

    // ---- layer 3 ----
    k_wrepack<<<8, 256, 0, stream>>>(W3, wb, stats);
    k_gemm_mfma<true><<<gemmGrid, 256, 0, stream>>>(hbf, wb, linb, N);
    k_agg<<<aggGrid, aggBlk, 0, stream>>>(linb, row_ptr, epair, dinv, b3, bufA, N);
    k_bnstats<<<STATS_GRID, 256, 0, stream>>>(bufA, N, stats);
    k_bnfinal<<<1, 128, 0, stream>>>(stats, g3, be3, ss, inv_n);
    k_post<<<postGrid, postBlk, 0, stream>>>(bufA, ss, bufC, bufA, hbf, N);     // h3: bufA + hbf

    // ---- output ----
    k_outgemm_mfma<<<gemmGrid, 256, 0, stream>>>(hbf, wob, bout, out, N);
}

// Round 7
// 472.025 us; speedup vs baseline: 2.8410x; 1.1585x over previous
//
#include <hip/hip_runtime.h>
#include <math.h>

#define DD 128
#define COUT 40
#define BN_EPS 1e-5f
#define L2_EPS 1e-12f

typedef __attribute__((ext_vector_type(8))) short bf16x8;
typedef __attribute__((ext_vector_type(4))) float f32x4;

static __device__ inline unsigned short f2bf(float f) {
    unsigned int x = __float_as_uint(f);
    unsigned int r = (x + 0x7FFFu + ((x >> 16) & 1u)) >> 16;   // RNE
    return (unsigned short)r;
}
static __device__ inline float bf2f(unsigned short u) {
    return __uint_as_float(((unsigned int)u) << 16);
}

// ---------------- setup kernels ----------------

__global__ void k_init(int* deg, int* fill, int n) {
    int i = blockIdx.x * blockDim.x + threadIdx.x;
    if (i < n) { deg[i] = 1; fill[i] = 0; }   // deg starts at 1 (self loop)
}

__global__ void k_hist(const int* ei, int E, int* deg) {
    int i = blockIdx.x * blockDim.x + threadIdx.x;
    if (i < E) atomicAdd(&deg[ei[E + i]], 1);   // dst = ei[E+i]
}

__global__ void k_dinv(const int* deg, float* dinv, int n) {
    int i = blockIdx.x * blockDim.x + threadIdx.x;
    if (i < n) dinv[i] = rsqrtf((float)deg[i]);
}

// exclusive scan over n+1 entries, 3 phases
__global__ void k_scan_a(const int* deg, int* row_ptr, int* bsum, int n) {
    __shared__ int s[256];
    int t = threadIdx.x;
    int idx = blockIdx.x * 256 + t;
    int v = (idx < n) ? deg[idx] : 0;
    s[t] = v; __syncthreads();
    for (int off = 1; off < 256; off <<= 1) {
        int x = (t >= off) ? s[t - off] : 0;
        __syncthreads(); s[t] += x; __syncthreads();
    }
    if (idx <= n) row_ptr[idx] = s[t] - v;     // local exclusive
    if (t == 255) bsum[blockIdx.x] = s[255];
}

__global__ void k_scan_b(const int* bsum, int* boff, int nb) {
    __shared__ int s[512];
    int t = threadIdx.x;
    int v = (t < nb) ? bsum[t] : 0;
    s[t] = v; __syncthreads();
    for (int off = 1; off < 512; off <<= 1) {
        int x = (t >= off) ? s[t - off] : 0;
        __syncthreads(); s[t] += x; __syncthreads();
    }
    if (t < nb) boff[t] = s[t] - v;            // exclusive block offsets
}

__global__ void k_scan_c(int* row_ptr, const int* boff, int n1) {
    int idx = blockIdx.x * blockDim.x + threadIdx.x;
    if (idx < n1) row_ptr[idx] += boff[idx >> 8];
}

// single 8B store per edge: epair[pos] = {src, bits(dinv[src])}
__global__ void k_fill(const int* ei, int E, int n, const int* row_ptr,
                       const float* dinv, int* fill, int2* epair) {
    int i = blockIdx.x * blockDim.x + threadIdx.x;
    int total = E + n;
    if (i >= total) return;
    int u, v;
    if (i < E) { u = ei[i]; v = ei[E + i]; }
    else { u = i - E; v = u; }                 // self loop
    int p = atomicAdd(&fill[v], 1);
    int pos = row_ptr[v] + p;
    int2 pr; pr.x = u; pr.y = __float_as_int(dinv[u]);
    epair[pos] = pr;
}

// One dispatch: repack W1/W2/W3 (blocks 0..23), Wout (24..26), zero stats (27).
// W layout in: [k][n] fp32 row-major. out: bf16 B-fragment order
//   wb[wi][((kc*8+cc)*64 + lane)*8 + j] = bf16(W[(kc*32+(lane>>4)*8+j)*128 + cc*16+(lane&15)])
__global__ void k_wrepack_all(const float* __restrict__ W1, const float* __restrict__ W2,
                              const float* __restrict__ W3, const float* __restrict__ Wout,
                              unsigned short* __restrict__ wb,    // 3 * 16384
                              unsigned short* __restrict__ wob,   // 6144
                              float* __restrict__ stats) {        // 768
    int b = blockIdx.x;
    if (b < 24) {
        int wi = b >> 3;
        const float* W = (wi == 0) ? W1 : (wi == 1) ? W2 : W3;
        unsigned short* out = wb + wi * 16384;
        int idx = (b & 7) * 256 + threadIdx.x;      // 0..2047
        int kc = idx >> 9;
        int cc = (idx >> 6) & 7;
        int lane = idx & 63;
        int n = cc * 16 + (lane & 15);
        int kb = kc * 32 + (lane >> 4) * 8;
        unsigned short tmp[8];
#pragma unroll
        for (int j = 0; j < 8; j++) tmp[j] = f2bf(W[(size_t)(kb + j) * DD + n]);
        *(uint4*)&out[(size_t)idx * 8] = *(const uint4*)tmp;
    } else if (b < 27) {
        int idx = (b - 24) * 256 + threadIdx.x;     // 0..767
        int kc = idx / 192;
        int rem = idx % 192;
        int cc = rem >> 6;
        int lane = rem & 63;
        int n = cc * 16 + (lane & 15);
        int kb = kc * 32 + (lane >> 4) * 8;
        unsigned short tmp[8];
#pragma unroll
        for (int j = 0; j < 8; j++)
            tmp[j] = (n < COUT) ? f2bf(Wout[(size_t)(kb + j) * COUT + n]) : 0;
        *(uint4*)&wob[(size_t)idx * 8] = *(const uint4*)tmp;
    } else {
        stats[threadIdx.x] = 0.f;
        stats[256 + threadIdx.x] = 0.f;
        stats[512 + threadIdx.x] = 0.f;
    }
}

// ---------------- compute kernels ----------------

// linb(bf16) = x(fp32) @ W1 via MFMA. Block = 4 waves, 64 rows. Layer-1 only.
__global__ __launch_bounds__(256) void k_gemm0(const float* __restrict__ A,
                                               const unsigned short* __restrict__ Wb,
                                               unsigned short* __restrict__ C, int nrows) {
    __shared__ __align__(16) unsigned short Ws[16384];   // 32 KB
    const int tid = threadIdx.x;
    for (int i = tid; i < 2048; i += 256)
        ((uint4*)Ws)[i] = ((const uint4*)Wb)[i];
    __syncthreads();

    const int wv = tid >> 6;
    const int lane = tid & 63;
    const int R0 = blockIdx.x * 64 + wv * 16;
    if (R0 >= nrows) return;
    const int m = lane & 15, q = lane >> 4;
    int rr = R0 + m; if (rr >= nrows) rr = nrows - 1;
    const float* Ar = A + (size_t)rr * DD + q * 8;

    bf16x8 af[4];
#pragma unroll
    for (int kc = 0; kc < 4; kc++) {
        float4 lo = *(const float4*)(Ar + kc * 32);
        float4 hi = *(const float4*)(Ar + kc * 32 + 4);
        unsigned short t[8];
        t[0] = f2bf(lo.x); t[1] = f2bf(lo.y); t[2] = f2bf(lo.z); t[3] = f2bf(lo.w);
        t[4] = f2bf(hi.x); t[5] = f2bf(hi.y); t[6] = f2bf(hi.z); t[7] = f2bf(hi.w);
        af[kc] = *(const bf16x8*)t;
    }

    f32x4 acc[8];
#pragma unroll
    for (int cc = 0; cc < 8; cc++) acc[cc] = (f32x4){0.f, 0.f, 0.f, 0.f};
#pragma unroll
    for (int kc = 0; kc < 4; kc++)
#pragma unroll
        for (int cc = 0; cc < 8; cc++) {
            bf16x8 b = *(const bf16x8*)&Ws[(size_t)((kc * 8 + cc) * 64 + lane) * 8];
            acc[cc] = __builtin_amdgcn_mfma_f32_16x16x32_bf16(af[kc], b, acc[cc], 0, 0, 0);
        }

#pragma unroll
    for (int cc = 0; cc < 8; cc++)
#pragma unroll
        for (int i = 0; i < 4; i++) {
            int r = R0 + q * 4 + i;
            if (r < nrows) C[(size_t)r * DD + cc * 16 + m] = f2bf(acc[cc][i]);
        }
}

// outb(bf16)[v] = bias + dv * sum_j w_j * lin_bf16[u_j]; 2 nodes per wave
__global__ void k_agg(const unsigned short* __restrict__ lin, const int* __restrict__ row_ptr,
                      const int2* __restrict__ epair, const float* __restrict__ dinv,
                      const float* __restrict__ bias, unsigned short* __restrict__ outb, int n) {
    int lane = threadIdx.x;
    int half = lane >> 5;
    int li = lane & 31;
    int v = blockIdx.x * 8 + threadIdx.y * 2 + half;
    if (v >= n) return;
    int c = li * 4;
    int s = row_ptr[v], e = row_ptr[v + 1];
    float dv = dinv[v];
    float4 accA = *(const float4*)&bias[c];
    float4 accB = make_float4(0.f, 0.f, 0.f, 0.f);
    int j = s;
    for (; j + 1 < e; j += 2) {
        int2 p0 = epair[j], p1 = epair[j + 1];
        float w0 = dv * __int_as_float(p0.y);
        float w1 = dv * __int_as_float(p1.y);
        ushort4 t0 = *(const ushort4*)&lin[(size_t)p0.x * DD + c];
        ushort4 t1 = *(const ushort4*)&lin[(size_t)p1.x * DD + c];
        accA.x += w0 * bf2f(t0.x); accA.y += w0 * bf2f(t0.y);
        accA.z += w0 * bf2f(t0.z); accA.w += w0 * bf2f(t0.w);
        accB.x += w1 * bf2f(t1.x); accB.y += w1 * bf2f(t1.y);
        accB.z += w1 * bf2f(t1.z); accB.w += w1 * bf2f(t1.w);
    }
    if (j < e) {
        int2 p = epair[j];
        float w = dv * __int_as_float(p.y);
        ushort4 t = *(const ushort4*)&lin[(size_t)p.x * DD + c];
        accA.x += w * bf2f(t.x); accA.y += w * bf2f(t.y);
        accA.z += w * bf2f(t.z); accA.w += w * bf2f(t.w);
    }
    accA.x += accB.x; accA.y += accB.y; accA.z += accB.z; accA.w += accB.w;
    ushort4 o;
    o.x = f2bf(accA.x); o.y = f2bf(accA.y); o.z = f2bf(accA.z); o.w = f2bf(accA.w);
    *(ushort4*)&outb[(size_t)v * DD + c] = o;
}

// stats[c] += col sums, stats[128+c] += col sumsq over bf16 X (LDS-reduced per block)
__global__ __launch_bounds__(256) void k_bnstats(const unsigned short* __restrict__ X, int n,
                                                 float* __restrict__ stats) {
    int cg = (threadIdx.x & 31) * 4;
    int rg = threadIdx.x >> 5;
    float s0 = 0, s1 = 0, s2 = 0, s3 = 0;
    float q0 = 0, q1 = 0, q2 = 0, q3 = 0;
    for (int r = blockIdx.x * 8 + rg; r < n; r += gridDim.x * 8) {
        ushort4 xv = *(const ushort4*)&X[(size_t)r * DD + cg];
        float x0 = bf2f(xv.x), x1 = bf2f(xv.y), x2 = bf2f(xv.z), x3 = bf2f(xv.w);
        s0 += x0; s1 += x1; s2 += x2; s3 += x3;
        q0 += x0 * x0; q1 += x1 * x1; q2 += x2 * x2; q3 += x3 * x3;
    }
    __shared__ float sh[8][128];
    __shared__ float qh[8][128];
    sh[rg][cg] = s0; sh[rg][cg + 1] = s1; sh[rg][cg + 2] = s2; sh[rg][cg + 3] = s3;
    qh[rg][cg] = q0; qh[rg][cg + 1] = q1; qh[rg][cg + 2] = q2; qh[rg][cg + 3] = q3;
    __syncthreads();
    if (threadIdx.x < 128) {
        float a = 0, b = 0;
        for (int g = 0; g < 8; g++) { a += sh[g][threadIdx.x]; b += qh[g][threadIdx.x]; }
        atomicAdd(&stats[threadIdx.x], a);
        atomicAdd(&stats[128 + threadIdx.x], b);
    }
}

// Fused: h = l2norm(relu(bn(aggX)) [+ res]);  hbf_out = bf16(h);  linb_out = h @ W.
// Each lane holds 32 of its row's 128 cols (q-slices); row sumsq via 2 shfl_xor.
template <bool HAS_RES>
__global__ __launch_bounds__(256) void k_fused(const unsigned short* __restrict__ aggX,
                                               const float* __restrict__ stats,
                                               const float* __restrict__ g,
                                               const float* __restrict__ be, float inv_n,
                                               const unsigned short* __restrict__ resb,
                                               const unsigned short* __restrict__ Wb,
                                               unsigned short* __restrict__ hbf_out,
                                               unsigned short* __restrict__ linb_out,
                                               int nrows) {
    __shared__ __align__(16) unsigned short Ws[16384];
    __shared__ float ssl[256];          // scale / shift
    const int tid = threadIdx.x;
    for (int i = tid; i < 2048; i += 256)
        ((uint4*)Ws)[i] = ((const uint4*)Wb)[i];
    if (tid < 128) {
        float mu = stats[tid] * inv_n;
        float var = stats[128 + tid] * inv_n - mu * mu;
        float sc = g[tid] * rsqrtf(var + BN_EPS);
        ssl[tid] = sc;
        ssl[128 + tid] = be[tid] - mu * sc;
    }
    __syncthreads();

    const int wv = tid >> 6;
    const int lane = tid & 63;
    const int R0 = blockIdx.x * 64 + wv * 16;
    if (R0 >= nrows) return;
    const int m = lane & 15, q = lane >> 4;
    int rr = R0 + m; if (rr >= nrows) rr = nrows - 1;
    const unsigned short* Ar = aggX + (size_t)rr * DD + q * 8;
    const unsigned short* Rr = HAS_RES ? resb + (size_t)rr * DD + q * 8 : nullptr;

    float y[4][8];
    float sq = 0.f;
#pragma unroll
    for (int kc = 0; kc < 4; kc++) {
        ushort4 lo = *(const ushort4*)(Ar + kc * 32);
        ushort4 hi = *(const ushort4*)(Ar + kc * 32 + 4);
        unsigned short av[8] = {lo.x, lo.y, lo.z, lo.w, hi.x, hi.y, hi.z, hi.w};
        int c0 = kc * 32 + q * 8;
        float4 sc0 = *(const float4*)&ssl[c0];
        float4 sc1 = *(const float4*)&ssl[c0 + 4];
        float4 sh0 = *(const float4*)&ssl[128 + c0];
        float4 sh1 = *(const float4*)&ssl[128 + c0 + 4];
        float scv[8] = {sc0.x, sc0.y, sc0.z, sc0.w, sc1.x, sc1.y, sc1.z, sc1.w};
        float shv[8] = {sh0.x, sh0.y, sh0.z, sh0.w, sh1.x, sh1.y, sh1.z, sh1.w};
        if (HAS_RES) {
            ushort4 rl = *(const ushort4*)(Rr + kc * 32);
            ushort4 rh = *(const ushort4*)(Rr + kc * 32 + 4);
            unsigned short rv[8] = {rl.x, rl.y, rl.z, rl.w, rh.x, rh.y, rh.z, rh.w};
#pragma unroll
            for (int j = 0; j < 8; j++) {
                float yy = fmaxf(bf2f(av[j]) * scv[j] + shv[j], 0.f) + bf2f(rv[j]);
                y[kc][j] = yy; sq += yy * yy;
            }
        } else {
#pragma unroll
            for (int j = 0; j < 8; j++) {
                float yy = fmaxf(bf2f(av[j]) * scv[j] + shv[j], 0.f);
                y[kc][j] = yy; sq += yy * yy;
            }
        }
    }
    sq += __shfl_xor(sq, 16, 64);
    sq += __shfl_xor(sq, 32, 64);
    float inv = 1.f / fmaxf(sqrtf(sq), L2_EPS);

    bf16x8 af[4];
#pragma unroll
    for (int kc = 0; kc < 4; kc++) {
        unsigned short t[8];
#pragma unroll
        for (int j = 0; j < 8; j++) t[j] = f2bf(y[kc][j] * inv);
        af[kc] = *(const bf16x8*)t;
        *(bf16x8*)&hbf_out[(size_t)rr * DD + q * 8 + kc * 32] = af[kc];
    }

    f32x4 acc[8];
#pragma unroll
    for (int cc = 0; cc < 8; cc++) acc[cc] = (f32x4){0.f, 0.f, 0.f, 0.f};
#pragma unroll
    for (int kc = 0; kc < 4; kc++)
#pragma unroll
        for (int cc = 0; cc < 8; cc++) {
            bf16x8 b = *(const bf16x8*)&Ws[(size_t)((kc * 8 + cc) * 64 + lane) * 8];
            acc[cc] = __builtin_amdgcn_mfma_f32_16x16x32_bf16(af[kc], b, acc[cc], 0, 0, 0);
        }

#pragma unroll
    for (int cc = 0; cc < 8; cc++)
#pragma unroll
        for (int i = 0; i < 4; i++) {
            int r = R0 + q * 4 + i;
            if (r < nrows) linb_out[(size_t)r * DD + cc * 16 + m] = f2bf(acc[cc][i]);
        }
}

// Fused output: h3 = l2norm(relu(bn(aggX)) + res);  out = h3 @ Wout + bout (fp32)
__global__ __launch_bounds__(256) void k_outfused(const unsigned short* __restrict__ aggX,
                                                  const float* __restrict__ stats,
                                                  const float* __restrict__ g,
                                                  const float* __restrict__ be, float inv_n,
                                                  const unsigned short* __restrict__ resb,
                                                  const unsigned short* __restrict__ wob,
                                                  const float* __restrict__ bout,
                                                  float* __restrict__ C, int nrows) {
    __shared__ __align__(16) unsigned short Ws[6144];
    __shared__ float ssl[256];
    const int tid = threadIdx.x;
    for (int i = tid; i < 768; i += 256)
        ((uint4*)Ws)[i] = ((const uint4*)wob)[i];
    if (tid < 128) {
        float mu = stats[tid] * inv_n;
        float var = stats[128 + tid] * inv_n - mu * mu;
        float sc = g[tid] * rsqrtf(var + BN_EPS);
        ssl[tid] = sc;
        ssl[128 + tid] = be[tid] - mu * sc;
    }
    __syncthreads();

    const int wv = tid >> 6;
    const int lane = tid & 63;
    const int R0 = blockIdx.x * 64 + wv * 16;
    if (R0 >= nrows) return;
    const int m = lane & 15, q = lane >> 4;
    int rr = R0 + m; if (rr >= nrows) rr = nrows - 1;
    const unsigned short* Ar = aggX + (size_t)rr * DD + q * 8;
    const unsigned short* Rr = resb + (size_t)rr * DD + q * 8;

    float y[4][8];
    float sq = 0.f;
#pragma unroll
    for (int kc = 0; kc < 4; kc++) {
        ushort4 lo = *(const ushort4*)(Ar + kc * 32);
        ushort4 hi = *(const ushort4*)(Ar + kc * 32 + 4);
        ushort4 rl = *(const ushort4*)(Rr + kc * 32);
        ushort4 rh = *(const ushort4*)(Rr + kc * 32 + 4);
        unsigned short av[8] = {lo.x, lo.y, lo.z, lo.w, hi.x, hi.y, hi.z, hi.w};
        unsigned short rv[8] = {rl.x, rl.y, rl.z, rl.w, rh.x, rh.y, rh.z, rh.w};
        int c0 = kc * 32 + q * 8;
        float4 sc0 = *(const float4*)&ssl[c0];
        float4 sc1 = *(const float4*)&ssl[c0 + 4];
        float4 sh0 = *(const float4*)&ssl[128 + c0];
        float4 sh1 = *(const float4*)&ssl[128 + c0 + 4];
        float scv[8] = {sc0.x, sc0.y, sc0.z, sc0.w, sc1.x, sc1.y, sc1.z, sc1.w};
        float shv[8] = {sh0.x, sh0.y, sh0.z, sh0.w, sh1.x, sh1.y, sh1.z, sh1.w};
#pragma unroll
        for (int j = 0; j < 8; j++) {
            float yy = fmaxf(bf2f(av[j]) * scv[j] + shv[j], 0.f) + bf2f(rv[j]);
            y[kc][j] = yy; sq += yy * yy;
        }
    }
    sq += __shfl_xor(sq, 16, 64);
    sq += __shfl_xor(sq, 32, 64);
    float inv = 1.f / fmaxf(sqrtf(sq), L2_EPS);

    bf16x8 af[4];
#pragma unroll
    for (int kc = 0; kc < 4; kc++) {
        unsigned short t[8];
#pragma unroll
        for (int j = 0; j < 8; j++) t[j] = f2bf(y[kc][j] * inv);
        af[kc] = *(const bf16x8*)t;
    }

    f32x4 acc[3];
#pragma unroll
    for (int cc = 0; cc < 3; cc++) acc[cc] = (f32x4){0.f, 0.f, 0.f, 0.f};
#pragma unroll
    for (int kc = 0; kc < 4; kc++)
#pragma unroll
        for (int cc = 0; cc < 3; cc++) {
            bf16x8 b = *(const bf16x8*)&Ws[(size_t)((kc * 3 + cc) * 64 + lane) * 8];
            acc[cc] = __builtin_amdgcn_mfma_f32_16x16x32_bf16(af[kc], b, acc[cc], 0, 0, 0);
        }

#pragma unroll
    for (int cc = 0; cc < 3; cc++) {
        int col = cc * 16 + m;
        if (col < COUT) {
            float bb = bout[col];
#pragma unroll
            for (int i = 0; i < 4; i++) {
                int r = R0 + q * 4 + i;
                if (r < nrows) C[(size_t)r * COUT + col] = acc[cc][i] + bb;
            }
        }
    }
}

// ---------------- host ----------------

extern "C" void kernel_launch(void* const* d_in, const int* in_sizes, int n_in,
                              void* d_out, int out_size, void* d_ws, size_t ws_size,
                              hipStream_t stream) {
    const float* x    = (const float*)d_in[0];
    const int*   ei   = (const int*)d_in[1];
    const float* W1   = (const float*)d_in[2];
    const float* b1   = (const float*)d_in[3];
    const float* W2   = (const float*)d_in[4];
    const float* b2   = (const float*)d_in[5];
    const float* W3   = (const float*)d_in[6];
    const float* b3   = (const float*)d_in[7];
    const float* g1   = (const float*)d_in[8];
    const float* be1  = (const float*)d_in[9];
    const float* g2   = (const float*)d_in[10];
    const float* be2  = (const float*)d_in[11];
    const float* g3   = (const float*)d_in[12];
    const float* be3  = (const float*)d_in[13];
    const float* Wout = (const float*)d_in[14];
    const float* bout = (const float*)d_in[15];
    float* out = (float*)d_out;

    const int N = in_sizes[0] / DD;
    const int E = in_sizes[1] / 2;
    const int NNZ = E + N;

    // workspace layout
    char* w = (char*)d_ws;
    unsigned short* linb = (unsigned short*)w; w += (size_t)N * DD * sizeof(unsigned short);
    unsigned short* aggA = (unsigned short*)w; w += (size_t)N * DD * sizeof(unsigned short);
    unsigned short* aggB = (unsigned short*)w; w += (size_t)N * DD * sizeof(unsigned short);
    unsigned short* hbf1 = (unsigned short*)w; w += (size_t)N * DD * sizeof(unsigned short);
    unsigned short* hbf2 = (unsigned short*)w; w += (size_t)N * DD * sizeof(unsigned short);
    unsigned short* wb   = (unsigned short*)w; w += 3 * 16384 * sizeof(unsigned short);
    unsigned short* wob  = (unsigned short*)w; w += 6144 * sizeof(unsigned short);
    int2* epair  = (int2*)w;                   w += (size_t)NNZ * sizeof(int2);
    int* deg     = (int*)w;                    w += (size_t)N * sizeof(int);
    int* fill    = (int*)w;                    w += (size_t)N * sizeof(int);
    int* row_ptr = (int*)w;                    w += (size_t)(N + 1) * sizeof(int);
    float* dinv  = (float*)w;                  w += (size_t)N * sizeof(float);
    int* bsum    = (int*)w;                    w += 512 * sizeof(int);
    int* boff    = (int*)w;                    w += 512 * sizeof(int);
    float* stats = (float*)w;                  w += 768 * sizeof(float);

    const int NB = (N + 1 + 255) / 256;      // scan blocks
    const int STATS_GRID = 128;

    // ---- CSR build + weight repack ----
    k_init<<<(N + 255) / 256, 256, 0, stream>>>(deg, fill, N);
    k_hist<<<(E + 255) / 256, 256, 0, stream>>>(ei, E, deg);
    k_dinv<<<(N + 255) / 256, 256, 0, stream>>>(deg, dinv, N);
    k_scan_a<<<NB, 256, 0, stream>>>(deg, row_ptr, bsum, N);
    k_scan_b<<<1, 512, 0, stream>>>(bsum, boff, NB);
    k_scan_c<<<(N + 1 + 255) / 256, 256, 0, stream>>>(row_ptr, boff, N + 1);
    k_fill<<<(NNZ + 255) / 256, 256, 0, stream>>>(ei, E, N, row_ptr, dinv, fill, epair);
    k_wrepack_all<<<28, 256, 0, stream>>>(W1, W2, W3, Wout, wb, wob, stats);

    int gemmGrid = (N + 63) / 64;
    dim3 aggGrid((N + 7) / 8);
    dim3 aggBlk(64, 4);
    float inv_n = 1.0f / (float)N;

    // ---- layer 1 ----
    k_gemm0<<<gemmGrid, 256, 0, stream>>>(x, wb, linb, N);
    k_agg<<<aggGrid, aggBlk, 0, stream>>>(linb, row_ptr, epair, dinv, b1, aggA, N);
    k_bnstats<<<STATS_GRID, 256, 0, stream>>>(aggA, N, stats);
    // ---- layer 2 (post1 fused into gemm2) ----
    k_fused<false><<<gemmGrid, 256, 0, stream>>>(aggA, stats, g1, be1, inv_n,
                                                 nullptr, wb + 16384, hbf1, linb, N);
    k_agg<<<aggGrid, aggBlk, 0, stream>>>(linb, row_ptr, epair, dinv, b2, aggB, N);
    k_bnstats<<<STATS_GRID, 256, 0, stream>>>(aggB, N, stats + 256);
    // ---- layer 3 (post2 fused into gemm3) ----
    k_fused<true><<<gemmGrid, 256, 0, stream>>>(aggB, stats + 256, g2, be2, inv_n,
                                                hbf1, wb + 32768, hbf2, linb, N);
    k_agg<<<aggGrid, aggBlk, 0, stream>>>(linb, row_ptr, epair, dinv, b3, aggA, N);
    k_bnstats<<<STATS_GRID, 256, 0, stream>>>(aggA, N, stats + 512);
    // ---- output (post3 fused into output GEMM) ----
    k_outfused<<<gemmGrid, 256, 0, stream>>>(aggA, stats + 512, g3, be3, inv_n,
                                             hbf2, wob, bout, out, N);
}